// Round 1
// baseline (1048.873 us; speedup 1.0000x reference)
//
#include <hip/hip_runtime.h>
#include <hip/hip_bf16.h>

#define NHID 128

// ---------------- CSR build ----------------
__global__ void hist_kernel(const int* __restrict__ dst, int E, int* __restrict__ counts) {
    for (int e = blockIdx.x * blockDim.x + threadIdx.x; e < E; e += gridDim.x * blockDim.x)
        atomicAdd(&counts[dst[e]], 1);
}

__global__ __launch_bounds__(1024) void scan_kernel(const int* __restrict__ counts,
                                                    int* __restrict__ row_ptr,
                                                    int* __restrict__ cursor, int n) {
    __shared__ int s[1024];
    int t = threadIdx.x;
    int chunk = (n + 1023) / 1024;
    int b = t * chunk;
    int e = min(n, b + chunk);
    int sum = 0;
    for (int i = b; i < e; ++i) sum += counts[i];
    s[t] = sum;
    __syncthreads();
    // Hillis-Steele inclusive scan
    for (int off = 1; off < 1024; off <<= 1) {
        int v = (t >= off) ? s[t - off] : 0;
        __syncthreads();
        s[t] += v;
        __syncthreads();
    }
    int run = (t == 0) ? 0 : s[t - 1];
    for (int i = b; i < e; ++i) {
        row_ptr[i] = run;
        cursor[i] = run;
        run += counts[i];
    }
    if (t == 1023) row_ptr[n] = s[1023];
}

__global__ void scatter_kernel(const int* __restrict__ src, const int* __restrict__ dst,
                               const float* __restrict__ w, int E,
                               int* __restrict__ cursor, int* __restrict__ src_s,
                               float* __restrict__ w_s) {
    for (int e = blockIdx.x * blockDim.x + threadIdx.x; e < E; e += gridDim.x * blockDim.x) {
        int d = dst[e];
        int pos = atomicAdd(&cursor[d], 1);
        src_s[pos] = src[e];
        w_s[pos] = w[e];
    }
}

// ---------------- SpMM: out[node] = sum_e w_e * X[src_e]  (one wave per node) ----------------
__global__ __launch_bounds__(256) void spmm_csr(const float* __restrict__ X,
                                                const int* __restrict__ src_s,
                                                const float* __restrict__ w_s,
                                                const int* __restrict__ row_ptr,
                                                float* __restrict__ out, int n) {
    int node = blockIdx.x * 4 + (threadIdx.x >> 6);
    if (node >= n) return;
    int lane = threadIdx.x & 63;
    int beg = row_ptr[node];
    int end = row_ptr[node + 1];
    float2 acc = make_float2(0.f, 0.f);
    for (int e0 = beg; e0 < end; e0 += 64) {
        int cnt = min(64, end - e0);
        int s = 0;
        float ww = 0.f;
        if (lane < cnt) {
            s = src_s[e0 + lane];
            ww = w_s[e0 + lane];
        }
        for (int i = 0; i < cnt; ++i) {
            int si = __shfl(s, i, 64);
            float wi = __shfl(ww, i, 64);
            const float2 v = *reinterpret_cast<const float2*>(&X[(size_t)si * NHID + lane * 2]);
            acc.x += wi * v.x;
            acc.y += wi * v.y;
        }
    }
    *reinterpret_cast<float2*>(&out[(size_t)node * NHID + lane * 2]) = acc;
}

// ---------------- GEMM + bias + ReLU: out = relu(X[nrows,128] @ W[128,DOUT] + b) ----------------
// block = 128 threads (2 waves), 32 rows per block, each wave owns 16 rows,
// each lane owns one output column per 64-wide column tile.
template <int DOUT>
__global__ __launch_bounds__(128) void gemm_bias_relu(const float* __restrict__ X,
                                                      const float* __restrict__ W,
                                                      const float* __restrict__ bias,
                                                      float* __restrict__ out, int nrows) {
    __shared__ float xsT[128][34];  // [k][r], padded
    __shared__ float Ws[128][64];   // [k][j] for current 64-col tile
    int row0 = blockIdx.x * 32;
    int tid = threadIdx.x;

    // stage 32 rows of X, transposed
    for (int idx = tid; idx < 32 * 128; idx += 128) {
        int r = idx >> 7, k = idx & 127;
        float v = (row0 + r < nrows) ? X[(size_t)(row0 + r) * 128 + k] : 0.f;
        xsT[k][r] = v;
    }

    int wave = tid >> 6;
    int lane = tid & 63;
    int rbase = wave * 16;

    for (int t = 0; t < DOUT / 64; ++t) {
        __syncthreads();
        // stage W column tile
        for (int idx = tid; idx < 128 * 64; idx += 128) {
            int k = idx >> 6, j = idx & 63;
            Ws[k][j] = W[(size_t)k * DOUT + t * 64 + j];
        }
        __syncthreads();

        float acc[16];
#pragma unroll
        for (int r = 0; r < 16; ++r) acc[r] = 0.f;

#pragma unroll 4
        for (int k = 0; k < 128; ++k) {
            float wk = Ws[k][lane];
#pragma unroll
            for (int r = 0; r < 16; ++r) acc[r] += xsT[k][rbase + r] * wk;
        }

        float bj = bias[t * 64 + lane];
#pragma unroll
        for (int r = 0; r < 16; ++r) {
            int row = row0 + rbase + r;
            if (row < nrows)
                out[(size_t)row * DOUT + t * 64 + lane] = fmaxf(acc[r] + bj, 0.f);
        }
    }
}

extern "C" void kernel_launch(void* const* d_in, const int* in_sizes, int n_in,
                              void* d_out, int out_size, void* d_ws, size_t ws_size,
                              hipStream_t stream) {
    const float* x  = (const float*)d_in[0];
    const float* ew = (const float*)d_in[1];
    const float* W1 = (const float*)d_in[2];
    const float* b1 = (const float*)d_in[3];
    const float* W2 = (const float*)d_in[4];
    const float* b2 = (const float*)d_in[5];
    const int*   ei = (const int*)d_in[6];

    const int N = in_sizes[0] / NHID;   // 100000
    const int E = in_sizes[1];          // 1600000
    const int* src = ei;
    const int* dst = ei + E;

    auto align256 = [](size_t v) { return (v + 255) & ~(size_t)255; };
    char* p = (char*)d_ws;
    float* g       = (float*)p; p += align256((size_t)N * NHID * 4);   // SpMM output (reused both layers)
    float* h       = (float*)p; p += align256((size_t)N * NHID * 4);   // hidden after layer 1
    int*   counts  = (int*)p;   p += align256((size_t)N * 4);
    int*   row_ptr = (int*)p;   p += align256((size_t)(N + 1) * 4);
    int*   cursor  = (int*)p;   p += align256((size_t)N * 4);
    int*   src_s   = (int*)p;   p += align256((size_t)E * 4);
    float* w_s     = (float*)p; p += align256((size_t)E * 4);

    // ---- CSR build (per call, deterministic work) ----
    hipMemsetAsync(counts, 0, (size_t)N * 4, stream);
    hist_kernel<<<2048, 256, 0, stream>>>(dst, E, counts);
    scan_kernel<<<1, 1024, 0, stream>>>(counts, row_ptr, cursor, N);
    scatter_kernel<<<2048, 256, 0, stream>>>(src, dst, ew, E, cursor, src_s, w_s);

    // ---- layer 1: h = relu((A @ x) @ W1 + b1) ----
    spmm_csr<<<(N + 3) / 4, 256, 0, stream>>>(x, src_s, w_s, row_ptr, g, N);
    gemm_bias_relu<128><<<(N + 31) / 32, 128, 0, stream>>>(g, W1, b1, h, N);

    // ---- layer 2: out = relu((A @ h) @ W2 + b2) ----
    spmm_csr<<<(N + 3) / 4, 256, 0, stream>>>(h, src_s, w_s, row_ptr, g, N);
    gemm_bias_relu<256><<<(N + 31) / 32, 128, 0, stream>>>(g, W2, b2, (float*)d_out, N);
}

// Round 2
// 820.362 us; speedup vs baseline: 1.2785x; 1.2785x over previous
//
#include <hip/hip_runtime.h>
#include <hip/hip_bf16.h>

#define NHID 128

// ---------------- CSR build ----------------
__global__ void hist_kernel(const int* __restrict__ dst, int E, int* __restrict__ counts) {
    for (int e = blockIdx.x * blockDim.x + threadIdx.x; e < E; e += gridDim.x * blockDim.x)
        atomicAdd(&counts[dst[e]], 1);
}

__global__ __launch_bounds__(1024) void scan_kernel(const int* __restrict__ counts,
                                                    int* __restrict__ row_ptr,
                                                    int* __restrict__ cursor, int n) {
    __shared__ int s[1024];
    int t = threadIdx.x;
    int chunk = (n + 1023) / 1024;
    int b = t * chunk;
    int e = min(n, b + chunk);
    int sum = 0;
    for (int i = b; i < e; ++i) sum += counts[i];
    s[t] = sum;
    __syncthreads();
    // Hillis-Steele inclusive scan
    for (int off = 1; off < 1024; off <<= 1) {
        int v = (t >= off) ? s[t - off] : 0;
        __syncthreads();
        s[t] += v;
        __syncthreads();
    }
    int run = (t == 0) ? 0 : s[t - 1];
    for (int i = b; i < e; ++i) {
        row_ptr[i] = run;
        cursor[i] = run;
        run += counts[i];
    }
    if (t == 1023) row_ptr[n] = s[1023];
}

__global__ void scatter_kernel(const int* __restrict__ src, const int* __restrict__ dst,
                               const float* __restrict__ w, int E,
                               int* __restrict__ cursor, int* __restrict__ src_s,
                               float* __restrict__ w_s) {
    for (int e = blockIdx.x * blockDim.x + threadIdx.x; e < E; e += gridDim.x * blockDim.x) {
        int d = dst[e];
        int pos = atomicAdd(&cursor[d], 1);
        src_s[pos] = src[e];
        w_s[pos] = w[e];
    }
}

// ---------------- SpMM: out[node] = sum_e w_e * X[src_e]  (one wave per node) ----------------
__global__ __launch_bounds__(256) void spmm_csr(const float* __restrict__ X,
                                                const int* __restrict__ src_s,
                                                const float* __restrict__ w_s,
                                                const int* __restrict__ row_ptr,
                                                float* __restrict__ out, int n) {
    int node = blockIdx.x * 4 + (threadIdx.x >> 6);
    if (node >= n) return;
    int lane = threadIdx.x & 63;
    int beg = row_ptr[node];
    int end = row_ptr[node + 1];
    float2 acc = make_float2(0.f, 0.f);
    for (int e0 = beg; e0 < end; e0 += 64) {
        int cnt = min(64, end - e0);
        int s = 0;
        float ww = 0.f;
        if (lane < cnt) {
            s = src_s[e0 + lane];
            ww = w_s[e0 + lane];
        }
        for (int i = 0; i < cnt; ++i) {
            int si = __shfl(s, i, 64);
            float wi = __shfl(ww, i, 64);
            const float2 v = *reinterpret_cast<const float2*>(&X[(size_t)si * NHID + lane * 2]);
            acc.x += wi * v.x;
            acc.y += wi * v.y;
        }
    }
    *reinterpret_cast<float2*>(&out[(size_t)node * NHID + lane * 2]) = acc;
}

// ---------------- GEMM + bias + ReLU: out = relu(X[nrows,128] @ W[128,DOUT] + b) ----------------
// BM=128, BN=128, BK=32. 256 threads. Each thread: 8x8 register tile in
// 2x2 quadrants of 4x4 (rows {tr*4, tr*4+64}, cols {tc*4, tc*4+64}) so each
// ds_read_b128 across the wave's 16 distinct addresses covers all 32 banks.
template <int DOUT>
__global__ __launch_bounds__(256) void gemm_bias_relu(const float* __restrict__ X,
                                                      const float* __restrict__ W,
                                                      const float* __restrict__ bias,
                                                      float* __restrict__ out, int nrows) {
    __shared__ float As[32][132];  // [k][r], padded (+4) to spread transpose-store banks
    __shared__ float Bs[32][128];  // [k][c]
    const int row0 = blockIdx.x * 128;
    const int col0 = blockIdx.y * 128;
    const int tid = threadIdx.x;
    const int tr = tid >> 4;   // 0..15
    const int tc = tid & 15;   // 0..15

    float acc[8][8];
#pragma unroll
    for (int i = 0; i < 8; ++i)
#pragma unroll
        for (int j = 0; j < 8; ++j) acc[i][j] = 0.f;

    for (int k0 = 0; k0 < 128; k0 += 32) {
        __syncthreads();  // protect previous iteration's reads
        // Stage As (transposed): 32k x 128r. Each thread: 4 float4 global loads.
#pragma unroll
        for (int i = 0; i < 4; ++i) {
            int q = tid + i * 256;      // 0..1023
            int r = q >> 3;             // 0..127
            int kq = q & 7;             // 0..7 (quad of k)
            int row = row0 + r;
            float4 v = make_float4(0.f, 0.f, 0.f, 0.f);
            if (row < nrows) v = *reinterpret_cast<const float4*>(&X[(size_t)row * 128 + k0 + kq * 4]);
            As[kq * 4 + 0][r] = v.x;
            As[kq * 4 + 1][r] = v.y;
            As[kq * 4 + 2][r] = v.z;
            As[kq * 4 + 3][r] = v.w;
        }
        // Stage Bs: direct copy, coalesced float4.
#pragma unroll
        for (int i = 0; i < 4; ++i) {
            int q = tid + i * 256;
            int k = q >> 5;             // 0..31
            int cq = q & 31;            // 0..31
            *reinterpret_cast<float4*>(&Bs[k][cq * 4]) =
                *reinterpret_cast<const float4*>(&W[(size_t)(k0 + k) * DOUT + col0 + cq * 4]);
        }
        __syncthreads();

#pragma unroll
        for (int k = 0; k < 32; ++k) {
            float4 a0 = *reinterpret_cast<const float4*>(&As[k][tr * 4]);
            float4 a1 = *reinterpret_cast<const float4*>(&As[k][tr * 4 + 64]);
            float4 b0 = *reinterpret_cast<const float4*>(&Bs[k][tc * 4]);
            float4 b1 = *reinterpret_cast<const float4*>(&Bs[k][tc * 4 + 64]);
            float a[8] = {a0.x, a0.y, a0.z, a0.w, a1.x, a1.y, a1.z, a1.w};
            float b[8] = {b0.x, b0.y, b0.z, b0.w, b1.x, b1.y, b1.z, b1.w};
#pragma unroll
            for (int i = 0; i < 8; ++i)
#pragma unroll
                for (int j = 0; j < 8; ++j) acc[i][j] += a[i] * b[j];
        }
    }

    // Epilogue: bias + ReLU, float4 stores.
    float bj[8];
#pragma unroll
    for (int jh = 0; jh < 2; ++jh)
#pragma unroll
        for (int j = 0; j < 4; ++j) bj[jh * 4 + j] = bias[col0 + jh * 64 + tc * 4 + j];

#pragma unroll
    for (int ih = 0; ih < 2; ++ih) {
#pragma unroll
        for (int i = 0; i < 4; ++i) {
            int row = row0 + ih * 64 + tr * 4 + i;
            if (row >= nrows) continue;
#pragma unroll
            for (int jh = 0; jh < 2; ++jh) {
                float4 v;
                v.x = fmaxf(acc[ih * 4 + i][jh * 4 + 0] + bj[jh * 4 + 0], 0.f);
                v.y = fmaxf(acc[ih * 4 + i][jh * 4 + 1] + bj[jh * 4 + 1], 0.f);
                v.z = fmaxf(acc[ih * 4 + i][jh * 4 + 2] + bj[jh * 4 + 2], 0.f);
                v.w = fmaxf(acc[ih * 4 + i][jh * 4 + 3] + bj[jh * 4 + 3], 0.f);
                *reinterpret_cast<float4*>(&out[(size_t)row * DOUT + col0 + jh * 64 + tc * 4]) = v;
            }
        }
    }
}

extern "C" void kernel_launch(void* const* d_in, const int* in_sizes, int n_in,
                              void* d_out, int out_size, void* d_ws, size_t ws_size,
                              hipStream_t stream) {
    const float* x  = (const float*)d_in[0];
    const float* ew = (const float*)d_in[1];
    const float* W1 = (const float*)d_in[2];
    const float* b1 = (const float*)d_in[3];
    const float* W2 = (const float*)d_in[4];
    const float* b2 = (const float*)d_in[5];
    const int*   ei = (const int*)d_in[6];

    const int N = in_sizes[0] / NHID;   // 100000
    const int E = in_sizes[1];          // 1600000
    const int* src = ei;
    const int* dst = ei + E;

    auto align256 = [](size_t v) { return (v + 255) & ~(size_t)255; };
    char* p = (char*)d_ws;
    float* g       = (float*)p; p += align256((size_t)N * NHID * 4);   // SpMM output (reused both layers)
    float* h       = (float*)p; p += align256((size_t)N * NHID * 4);   // hidden after layer 1
    int*   counts  = (int*)p;   p += align256((size_t)N * 4);
    int*   row_ptr = (int*)p;   p += align256((size_t)(N + 1) * 4);
    int*   cursor  = (int*)p;   p += align256((size_t)N * 4);
    int*   src_s   = (int*)p;   p += align256((size_t)E * 4);
    float* w_s     = (float*)p; p += align256((size_t)E * 4);

    // ---- CSR build (per call, deterministic work) ----
    hipMemsetAsync(counts, 0, (size_t)N * 4, stream);
    hist_kernel<<<2048, 256, 0, stream>>>(dst, E, counts);
    scan_kernel<<<1, 1024, 0, stream>>>(counts, row_ptr, cursor, N);
    scatter_kernel<<<2048, 256, 0, stream>>>(src, dst, ew, E, cursor, src_s, w_s);

    // ---- layer 1: h = relu((A @ x) @ W1 + b1) ----
    spmm_csr<<<(N + 3) / 4, 256, 0, stream>>>(x, src_s, w_s, row_ptr, g, N);
    {
        dim3 grid((N + 127) / 128, 128 / 128);
        gemm_bias_relu<128><<<grid, 256, 0, stream>>>(g, W1, b1, h, N);
    }

    // ---- layer 2: out = relu((A @ h) @ W2 + b2) ----
    spmm_csr<<<(N + 3) / 4, 256, 0, stream>>>(h, src_s, w_s, row_ptr, g, N);
    {
        dim3 grid((N + 127) / 128, 256 / 128);
        gemm_bias_relu<256><<<grid, 256, 0, stream>>>(g, W2, b2, (float*)d_out, N);
    }
}

// Round 3
// 605.391 us; speedup vs baseline: 1.7326x; 1.3551x over previous
//
#include <hip/hip_runtime.h>
#include <hip/hip_bf16.h>

#define NHID 128

// ---------------- CSR build ----------------
__global__ void hist_kernel(const int* __restrict__ dst, int E, int* __restrict__ counts) {
    for (int e = blockIdx.x * blockDim.x + threadIdx.x; e < E; e += gridDim.x * blockDim.x)
        atomicAdd(&counts[dst[e]], 1);
}

// ---- 3-kernel device-wide exclusive scan over counts[n] -> row_ptr, cursor ----
// Elements per block = 256 threads * 8 = 2048. nb = ceil(n/2048) must be <= 64.

__global__ __launch_bounds__(256) void block_sum_kernel(const int* __restrict__ counts, int n,
                                                        int* __restrict__ bsums) {
    __shared__ int red[256];
    int tid = threadIdx.x;
    int base = blockIdx.x * 2048 + tid * 8;
    int s = 0;
#pragma unroll
    for (int i = 0; i < 8; ++i) {
        int idx = base + i;
        if (idx < n) s += counts[idx];
    }
    red[tid] = s;
    __syncthreads();
    for (int off = 128; off > 0; off >>= 1) {
        if (tid < off) red[tid] += red[tid + off];
        __syncthreads();
    }
    if (tid == 0) bsums[blockIdx.x] = red[0];
}

__global__ void scan_bsums_kernel(const int* __restrict__ bsums, int nb, int* __restrict__ boffs) {
    int lane = threadIdx.x;  // 64 threads
    int orig = (lane < nb) ? bsums[lane] : 0;
    int v = orig;
#pragma unroll
    for (int off = 1; off < 64; off <<= 1) {
        int u = __shfl_up(v, off, 64);
        if (lane >= off) v += u;
    }
    if (lane < nb) boffs[lane] = v - orig;   // exclusive block offset
    if (lane == 63) boffs[nb] = v;           // grand total
}

__global__ __launch_bounds__(256) void scan_write_kernel(const int* __restrict__ counts, int n,
                                                         const int* __restrict__ boffs, int nb,
                                                         int* __restrict__ row_ptr,
                                                         int* __restrict__ cursor) {
    __shared__ int wsum[4];
    int tid = threadIdx.x;
    int lane = tid & 63;
    int wv = tid >> 6;
    int base = blockIdx.x * 2048 + tid * 8;

    int v[8];
    int s = 0;
#pragma unroll
    for (int i = 0; i < 8; ++i) {
        int idx = base + i;
        v[i] = (idx < n) ? counts[idx] : 0;
        s += v[i];
    }
    // wave inclusive scan of per-thread sums
    int incl = s;
#pragma unroll
    for (int off = 1; off < 64; off <<= 1) {
        int u = __shfl_up(incl, off, 64);
        if (lane >= off) incl += u;
    }
    if (lane == 63) wsum[wv] = incl;
    __syncthreads();
    int wexcl = 0;
    for (int w = 0; w < wv; ++w) wexcl += wsum[w];

    int run = boffs[blockIdx.x] + wexcl + (incl - s);
#pragma unroll
    for (int i = 0; i < 8; ++i) {
        int idx = base + i;
        if (idx < n) {
            row_ptr[idx] = run;
            cursor[idx] = run;
        }
        run += v[i];
    }
    if (blockIdx.x == 0 && tid == 0) row_ptr[n] = boffs[nb];
}

__global__ void scatter_kernel(const int* __restrict__ src, const int* __restrict__ dst,
                               const float* __restrict__ w, int E,
                               int* __restrict__ cursor, int* __restrict__ src_s,
                               float* __restrict__ w_s) {
    for (int e = blockIdx.x * blockDim.x + threadIdx.x; e < E; e += gridDim.x * blockDim.x) {
        int d = dst[e];
        int pos = atomicAdd(&cursor[d], 1);
        src_s[pos] = src[e];
        w_s[pos] = w[e];
    }
}

// ---------------- SpMM: out[node] = sum_e w_e * X[src_e]  (one wave per node) ----------------
__global__ __launch_bounds__(256) void spmm_csr(const float* __restrict__ X,
                                                const int* __restrict__ src_s,
                                                const float* __restrict__ w_s,
                                                const int* __restrict__ row_ptr,
                                                float* __restrict__ out, int n) {
    int node = blockIdx.x * 4 + (threadIdx.x >> 6);
    if (node >= n) return;
    int lane = threadIdx.x & 63;
    int beg = row_ptr[node];
    int end = row_ptr[node + 1];
    float2 acc = make_float2(0.f, 0.f);
    for (int e0 = beg; e0 < end; e0 += 64) {
        int cnt = min(64, end - e0);
        int s = 0;
        float ww = 0.f;
        if (lane < cnt) {
            s = src_s[e0 + lane];
            ww = w_s[e0 + lane];
        }
        for (int i = 0; i < cnt; ++i) {
            int si = __shfl(s, i, 64);
            float wi = __shfl(ww, i, 64);
            const float2 v = *reinterpret_cast<const float2*>(&X[(size_t)si * NHID + lane * 2]);
            acc.x += wi * v.x;
            acc.y += wi * v.y;
        }
    }
    *reinterpret_cast<float2*>(&out[(size_t)node * NHID + lane * 2]) = acc;
}

// ---------------- GEMM + bias + ReLU: out = relu(X[nrows,128] @ W[128,DOUT] + b) ----------------
// BM=128, BN=128, BK=32. 256 threads. Each thread: 8x8 register tile in
// 2x2 quadrants of 4x4 (rows {tr*4, tr*4+64}, cols {tc*4, tc*4+64}).
template <int DOUT>
__global__ __launch_bounds__(256) void gemm_bias_relu(const float* __restrict__ X,
                                                      const float* __restrict__ W,
                                                      const float* __restrict__ bias,
                                                      float* __restrict__ out, int nrows) {
    __shared__ float As[32][132];  // [k][r], padded
    __shared__ float Bs[32][128];  // [k][c]
    const int row0 = blockIdx.x * 128;
    const int col0 = blockIdx.y * 128;
    const int tid = threadIdx.x;
    const int tr = tid >> 4;   // 0..15
    const int tc = tid & 15;   // 0..15

    float acc[8][8];
#pragma unroll
    for (int i = 0; i < 8; ++i)
#pragma unroll
        for (int j = 0; j < 8; ++j) acc[i][j] = 0.f;

    for (int k0 = 0; k0 < 128; k0 += 32) {
        __syncthreads();
#pragma unroll
        for (int i = 0; i < 4; ++i) {
            int q = tid + i * 256;      // 0..1023
            int r = q >> 3;             // 0..127
            int kq = q & 7;             // 0..7
            int row = row0 + r;
            float4 v = make_float4(0.f, 0.f, 0.f, 0.f);
            if (row < nrows) v = *reinterpret_cast<const float4*>(&X[(size_t)row * 128 + k0 + kq * 4]);
            As[kq * 4 + 0][r] = v.x;
            As[kq * 4 + 1][r] = v.y;
            As[kq * 4 + 2][r] = v.z;
            As[kq * 4 + 3][r] = v.w;
        }
#pragma unroll
        for (int i = 0; i < 4; ++i) {
            int q = tid + i * 256;
            int k = q >> 5;             // 0..31
            int cq = q & 31;            // 0..31
            *reinterpret_cast<float4*>(&Bs[k][cq * 4]) =
                *reinterpret_cast<const float4*>(&W[(size_t)(k0 + k) * DOUT + col0 + cq * 4]);
        }
        __syncthreads();

#pragma unroll
        for (int k = 0; k < 32; ++k) {
            float4 a0 = *reinterpret_cast<const float4*>(&As[k][tr * 4]);
            float4 a1 = *reinterpret_cast<const float4*>(&As[k][tr * 4 + 64]);
            float4 b0 = *reinterpret_cast<const float4*>(&Bs[k][tc * 4]);
            float4 b1 = *reinterpret_cast<const float4*>(&Bs[k][tc * 4 + 64]);
            float a[8] = {a0.x, a0.y, a0.z, a0.w, a1.x, a1.y, a1.z, a1.w};
            float b[8] = {b0.x, b0.y, b0.z, b0.w, b1.x, b1.y, b1.z, b1.w};
#pragma unroll
            for (int i = 0; i < 8; ++i)
#pragma unroll
                for (int j = 0; j < 8; ++j) acc[i][j] += a[i] * b[j];
        }
    }

    float bj[8];
#pragma unroll
    for (int jh = 0; jh < 2; ++jh)
#pragma unroll
        for (int j = 0; j < 4; ++j) bj[jh * 4 + j] = bias[col0 + jh * 64 + tc * 4 + j];

#pragma unroll
    for (int ih = 0; ih < 2; ++ih) {
#pragma unroll
        for (int i = 0; i < 4; ++i) {
            int row = row0 + ih * 64 + tr * 4 + i;
            if (row >= nrows) continue;
#pragma unroll
            for (int jh = 0; jh < 2; ++jh) {
                float4 v;
                v.x = fmaxf(acc[ih * 4 + i][jh * 4 + 0] + bj[jh * 4 + 0], 0.f);
                v.y = fmaxf(acc[ih * 4 + i][jh * 4 + 1] + bj[jh * 4 + 1], 0.f);
                v.z = fmaxf(acc[ih * 4 + i][jh * 4 + 2] + bj[jh * 4 + 2], 0.f);
                v.w = fmaxf(acc[ih * 4 + i][jh * 4 + 3] + bj[jh * 4 + 3], 0.f);
                *reinterpret_cast<float4*>(&out[(size_t)row * DOUT + col0 + jh * 64 + tc * 4]) = v;
            }
        }
    }
}

extern "C" void kernel_launch(void* const* d_in, const int* in_sizes, int n_in,
                              void* d_out, int out_size, void* d_ws, size_t ws_size,
                              hipStream_t stream) {
    const float* x  = (const float*)d_in[0];
    const float* ew = (const float*)d_in[1];
    const float* W1 = (const float*)d_in[2];
    const float* b1 = (const float*)d_in[3];
    const float* W2 = (const float*)d_in[4];
    const float* b2 = (const float*)d_in[5];
    const int*   ei = (const int*)d_in[6];

    const int N = in_sizes[0] / NHID;   // 100000
    const int E = in_sizes[1];          // 1600000
    const int* src = ei;
    const int* dst = ei + E;

    auto align256 = [](size_t v) { return (v + 255) & ~(size_t)255; };
    char* p = (char*)d_ws;
    float* g       = (float*)p; p += align256((size_t)N * NHID * 4);
    float* h       = (float*)p; p += align256((size_t)N * NHID * 4);
    int*   counts  = (int*)p;   p += align256((size_t)N * 4);
    int*   row_ptr = (int*)p;   p += align256((size_t)(N + 1) * 4);
    int*   cursor  = (int*)p;   p += align256((size_t)N * 4);
    int*   src_s   = (int*)p;   p += align256((size_t)E * 4);
    float* w_s     = (float*)p; p += align256((size_t)E * 4);
    int*   bsums   = (int*)p;   p += align256((size_t)128 * 4);
    int*   boffs   = (int*)p;   p += align256((size_t)128 * 4);

    const int nb = (N + 2047) / 2048;   // 49 for N=100000 (must be <= 64)

    // ---- CSR build (per call, deterministic work) ----
    hipMemsetAsync(counts, 0, (size_t)N * 4, stream);
    hist_kernel<<<2048, 256, 0, stream>>>(dst, E, counts);
    block_sum_kernel<<<nb, 256, 0, stream>>>(counts, N, bsums);
    scan_bsums_kernel<<<1, 64, 0, stream>>>(bsums, nb, boffs);
    scan_write_kernel<<<nb, 256, 0, stream>>>(counts, N, boffs, nb, row_ptr, cursor);
    scatter_kernel<<<2048, 256, 0, stream>>>(src, dst, ew, E, cursor, src_s, w_s);

    // ---- layer 1: h = relu((A @ x) @ W1 + b1) ----
    spmm_csr<<<(N + 3) / 4, 256, 0, stream>>>(x, src_s, w_s, row_ptr, g, N);
    {
        dim3 grid((N + 127) / 128, 128 / 128);
        gemm_bias_relu<128><<<grid, 256, 0, stream>>>(g, W1, b1, h, N);
    }

    // ---- layer 2: out = relu((A @ h) @ W2 + b2) ----
    spmm_csr<<<(N + 3) / 4, 256, 0, stream>>>(h, src_s, w_s, row_ptr, g, N);
    {
        dim3 grid((N + 127) / 128, 256 / 128);
        gemm_bias_relu<256><<<grid, 256, 0, stream>>>(g, W2, b2, (float*)d_out, N);
    }
}

// Round 4
// 596.401 us; speedup vs baseline: 1.7587x; 1.0151x over previous
//
#include <hip/hip_runtime.h>
#include <hip/hip_bf16.h>

#define NHID 128

// ---------------- CSR build ----------------
__global__ void hist_kernel(const int* __restrict__ dst, int E, int* __restrict__ counts) {
    for (int e = blockIdx.x * blockDim.x + threadIdx.x; e < E; e += gridDim.x * blockDim.x)
        atomicAdd(&counts[dst[e]], 1);
}

// ---- 3-kernel device-wide exclusive scan over counts[n] -> row_ptr, cursor ----
__global__ __launch_bounds__(256) void block_sum_kernel(const int* __restrict__ counts, int n,
                                                        int* __restrict__ bsums) {
    __shared__ int red[256];
    int tid = threadIdx.x;
    int base = blockIdx.x * 2048 + tid * 8;
    int s = 0;
#pragma unroll
    for (int i = 0; i < 8; ++i) {
        int idx = base + i;
        if (idx < n) s += counts[idx];
    }
    red[tid] = s;
    __syncthreads();
    for (int off = 128; off > 0; off >>= 1) {
        if (tid < off) red[tid] += red[tid + off];
        __syncthreads();
    }
    if (tid == 0) bsums[blockIdx.x] = red[0];
}

__global__ void scan_bsums_kernel(const int* __restrict__ bsums, int nb, int* __restrict__ boffs) {
    int lane = threadIdx.x;  // 64 threads
    int orig = (lane < nb) ? bsums[lane] : 0;
    int v = orig;
#pragma unroll
    for (int off = 1; off < 64; off <<= 1) {
        int u = __shfl_up(v, off, 64);
        if (lane >= off) v += u;
    }
    if (lane < nb) boffs[lane] = v - orig;
    if (lane == 63) boffs[nb] = v;
}

__global__ __launch_bounds__(256) void scan_write_kernel(const int* __restrict__ counts, int n,
                                                         const int* __restrict__ boffs, int nb,
                                                         int* __restrict__ row_ptr,
                                                         int* __restrict__ cursor) {
    __shared__ int wsum[4];
    int tid = threadIdx.x;
    int lane = tid & 63;
    int wv = tid >> 6;
    int base = blockIdx.x * 2048 + tid * 8;

    int v[8];
    int s = 0;
#pragma unroll
    for (int i = 0; i < 8; ++i) {
        int idx = base + i;
        v[i] = (idx < n) ? counts[idx] : 0;
        s += v[i];
    }
    int incl = s;
#pragma unroll
    for (int off = 1; off < 64; off <<= 1) {
        int u = __shfl_up(incl, off, 64);
        if (lane >= off) incl += u;
    }
    if (lane == 63) wsum[wv] = incl;
    __syncthreads();
    int wexcl = 0;
    for (int w = 0; w < wv; ++w) wexcl += wsum[w];

    int run = boffs[blockIdx.x] + wexcl + (incl - s);
#pragma unroll
    for (int i = 0; i < 8; ++i) {
        int idx = base + i;
        if (idx < n) {
            row_ptr[idx] = run;
            cursor[idx] = run;
        }
        run += v[i];
    }
    if (blockIdx.x == 0 && tid == 0) row_ptr[n] = boffs[nb];
}

__global__ void scatter_kernel(const int* __restrict__ src, const int* __restrict__ dst,
                               const float* __restrict__ w, int E,
                               int* __restrict__ cursor, int* __restrict__ src_s,
                               float* __restrict__ w_s) {
    for (int e = blockIdx.x * blockDim.x + threadIdx.x; e < E; e += gridDim.x * blockDim.x) {
        int d = dst[e];
        int pos = atomicAdd(&cursor[d], 1);
        src_s[pos] = src[e];
        w_s[pos] = w[e];
    }
}

// ---------------- SpMM: out[node] = sum_e w_e * X[src_e]  (one wave per node) ----------------
// 2 edges per wave-wide load step: lane-half 0/1 -> edge pair, each lane float4.
// Unrolled to 8 edges (4 independent dwordx4 per lane in flight) to hide L2/L3 latency.
__global__ __launch_bounds__(256) void spmm_csr(const float* __restrict__ X,
                                                const int* __restrict__ src_s,
                                                const float* __restrict__ w_s,
                                                const int* __restrict__ row_ptr,
                                                float* __restrict__ out, int n) {
    int node = blockIdx.x * 4 + (threadIdx.x >> 6);
    if (node >= n) return;
    int lane = threadIdx.x & 63;
    int half = lane >> 5;      // 0 or 1
    int lq = lane & 31;        // 0..31 -> cols [lq*4, lq*4+3]
    int beg = row_ptr[node];
    int end = row_ptr[node + 1];

    float4 acc = make_float4(0.f, 0.f, 0.f, 0.f);

    for (int e0 = beg; e0 < end; e0 += 64) {
        int cnt = min(64, end - e0);
        int s = 0;
        float ww = 0.f;
        if (lane < cnt) {
            s = src_s[e0 + lane];
            ww = w_s[e0 + lane];
        }
        int i = 0;
        // 8 edges per iteration: 4 independent float4 loads per lane
        for (; i + 8 <= cnt; i += 8) {
            int sx[4];
            float wx[4];
#pragma unroll
            for (int u = 0; u < 4; ++u) {
                sx[u] = __shfl(s, i + 2 * u + half, 64);
                wx[u] = __shfl(ww, i + 2 * u + half, 64);
            }
            float4 v[4];
#pragma unroll
            for (int u = 0; u < 4; ++u)
                v[u] = *reinterpret_cast<const float4*>(&X[(size_t)sx[u] * NHID + lq * 4]);
#pragma unroll
            for (int u = 0; u < 4; ++u) {
                acc.x += wx[u] * v[u].x;
                acc.y += wx[u] * v[u].y;
                acc.z += wx[u] * v[u].z;
                acc.w += wx[u] * v[u].w;
            }
        }
        // 4-edge tail
        for (; i + 4 <= cnt; i += 4) {
            int s0 = __shfl(s, i + half, 64);
            float w0 = __shfl(ww, i + half, 64);
            int s1 = __shfl(s, i + 2 + half, 64);
            float w1 = __shfl(ww, i + 2 + half, 64);
            float4 v0 = *reinterpret_cast<const float4*>(&X[(size_t)s0 * NHID + lq * 4]);
            float4 v1 = *reinterpret_cast<const float4*>(&X[(size_t)s1 * NHID + lq * 4]);
            acc.x += w0 * v0.x + w1 * v1.x;
            acc.y += w0 * v0.y + w1 * v1.y;
            acc.z += w0 * v0.z + w1 * v1.z;
            acc.w += w0 * v0.w + w1 * v1.w;
        }
        // 2-edge tail
        for (; i + 2 <= cnt; i += 2) {
            int s0 = __shfl(s, i + half, 64);
            float w0 = __shfl(ww, i + half, 64);
            float4 v0 = *reinterpret_cast<const float4*>(&X[(size_t)s0 * NHID + lq * 4]);
            acc.x += w0 * v0.x;
            acc.y += w0 * v0.y;
            acc.z += w0 * v0.z;
            acc.w += w0 * v0.w;
        }
        // single-edge tail: only half 0 accumulates
        if (i < cnt) {
            int s0 = __shfl(s, i, 64);
            float w0 = __shfl(ww, i, 64);
            if (half == 0) {
                float4 v0 = *reinterpret_cast<const float4*>(&X[(size_t)s0 * NHID + lq * 4]);
                acc.x += w0 * v0.x;
                acc.y += w0 * v0.y;
                acc.z += w0 * v0.z;
                acc.w += w0 * v0.w;
            }
        }
    }

    // combine halves
    acc.x += __shfl_xor(acc.x, 32, 64);
    acc.y += __shfl_xor(acc.y, 32, 64);
    acc.z += __shfl_xor(acc.z, 32, 64);
    acc.w += __shfl_xor(acc.w, 32, 64);

    if (half == 0)
        *reinterpret_cast<float4*>(&out[(size_t)node * NHID + lq * 4]) = acc;
}

// ---------------- GEMM + bias + ReLU: out = relu(X[nrows,128] @ W[128,DOUT] + b) ----------------
template <int DOUT>
__global__ __launch_bounds__(256) void gemm_bias_relu(const float* __restrict__ X,
                                                      const float* __restrict__ W,
                                                      const float* __restrict__ bias,
                                                      float* __restrict__ out, int nrows) {
    __shared__ float As[32][132];
    __shared__ float Bs[32][128];
    const int row0 = blockIdx.x * 128;
    const int col0 = blockIdx.y * 128;
    const int tid = threadIdx.x;
    const int tr = tid >> 4;
    const int tc = tid & 15;

    float acc[8][8];
#pragma unroll
    for (int i = 0; i < 8; ++i)
#pragma unroll
        for (int j = 0; j < 8; ++j) acc[i][j] = 0.f;

    for (int k0 = 0; k0 < 128; k0 += 32) {
        __syncthreads();
#pragma unroll
        for (int i = 0; i < 4; ++i) {
            int q = tid + i * 256;
            int r = q >> 3;
            int kq = q & 7;
            int row = row0 + r;
            float4 v = make_float4(0.f, 0.f, 0.f, 0.f);
            if (row < nrows) v = *reinterpret_cast<const float4*>(&X[(size_t)row * 128 + k0 + kq * 4]);
            As[kq * 4 + 0][r] = v.x;
            As[kq * 4 + 1][r] = v.y;
            As[kq * 4 + 2][r] = v.z;
            As[kq * 4 + 3][r] = v.w;
        }
#pragma unroll
        for (int i = 0; i < 4; ++i) {
            int q = tid + i * 256;
            int k = q >> 5;
            int cq = q & 31;
            *reinterpret_cast<float4*>(&Bs[k][cq * 4]) =
                *reinterpret_cast<const float4*>(&W[(size_t)(k0 + k) * DOUT + col0 + cq * 4]);
        }
        __syncthreads();

#pragma unroll
        for (int k = 0; k < 32; ++k) {
            float4 a0 = *reinterpret_cast<const float4*>(&As[k][tr * 4]);
            float4 a1 = *reinterpret_cast<const float4*>(&As[k][tr * 4 + 64]);
            float4 b0 = *reinterpret_cast<const float4*>(&Bs[k][tc * 4]);
            float4 b1 = *reinterpret_cast<const float4*>(&Bs[k][tc * 4 + 64]);
            float a[8] = {a0.x, a0.y, a0.z, a0.w, a1.x, a1.y, a1.z, a1.w};
            float b[8] = {b0.x, b0.y, b0.z, b0.w, b1.x, b1.y, b1.z, b1.w};
#pragma unroll
            for (int i = 0; i < 8; ++i)
#pragma unroll
                for (int j = 0; j < 8; ++j) acc[i][j] += a[i] * b[j];
        }
    }

    float bj[8];
#pragma unroll
    for (int jh = 0; jh < 2; ++jh)
#pragma unroll
        for (int j = 0; j < 4; ++j) bj[jh * 4 + j] = bias[col0 + jh * 64 + tc * 4 + j];

#pragma unroll
    for (int ih = 0; ih < 2; ++ih) {
#pragma unroll
        for (int i = 0; i < 4; ++i) {
            int row = row0 + ih * 64 + tr * 4 + i;
            if (row >= nrows) continue;
#pragma unroll
            for (int jh = 0; jh < 2; ++jh) {
                float4 v;
                v.x = fmaxf(acc[ih * 4 + i][jh * 4 + 0] + bj[jh * 4 + 0], 0.f);
                v.y = fmaxf(acc[ih * 4 + i][jh * 4 + 1] + bj[jh * 4 + 1], 0.f);
                v.z = fmaxf(acc[ih * 4 + i][jh * 4 + 2] + bj[jh * 4 + 2], 0.f);
                v.w = fmaxf(acc[ih * 4 + i][jh * 4 + 3] + bj[jh * 4 + 3], 0.f);
                *reinterpret_cast<float4*>(&out[(size_t)row * DOUT + col0 + jh * 64 + tc * 4]) = v;
            }
        }
    }
}

extern "C" void kernel_launch(void* const* d_in, const int* in_sizes, int n_in,
                              void* d_out, int out_size, void* d_ws, size_t ws_size,
                              hipStream_t stream) {
    const float* x  = (const float*)d_in[0];
    const float* ew = (const float*)d_in[1];
    const float* W1 = (const float*)d_in[2];
    const float* b1 = (const float*)d_in[3];
    const float* W2 = (const float*)d_in[4];
    const float* b2 = (const float*)d_in[5];
    const int*   ei = (const int*)d_in[6];

    const int N = in_sizes[0] / NHID;   // 100000
    const int E = in_sizes[1];          // 1600000
    const int* src = ei;
    const int* dst = ei + E;

    auto align256 = [](size_t v) { return (v + 255) & ~(size_t)255; };
    char* p = (char*)d_ws;
    float* g       = (float*)p; p += align256((size_t)N * NHID * 4);
    float* h       = (float*)p; p += align256((size_t)N * NHID * 4);
    int*   counts  = (int*)p;   p += align256((size_t)N * 4);
    int*   row_ptr = (int*)p;   p += align256((size_t)(N + 1) * 4);
    int*   cursor  = (int*)p;   p += align256((size_t)N * 4);
    int*   src_s   = (int*)p;   p += align256((size_t)E * 4);
    float* w_s     = (float*)p; p += align256((size_t)E * 4);
    int*   bsums   = (int*)p;   p += align256((size_t)128 * 4);
    int*   boffs   = (int*)p;   p += align256((size_t)128 * 4);

    const int nb = (N + 2047) / 2048;   // 49 for N=100000

    // ---- CSR build ----
    hipMemsetAsync(counts, 0, (size_t)N * 4, stream);
    hist_kernel<<<2048, 256, 0, stream>>>(dst, E, counts);
    block_sum_kernel<<<nb, 256, 0, stream>>>(counts, N, bsums);
    scan_bsums_kernel<<<1, 64, 0, stream>>>(bsums, nb, boffs);
    scan_write_kernel<<<nb, 256, 0, stream>>>(counts, N, boffs, nb, row_ptr, cursor);
    scatter_kernel<<<2048, 256, 0, stream>>>(src, dst, ew, E, cursor, src_s, w_s);

    // ---- layer 1: h = relu((A @ x) @ W1 + b1) ----
    spmm_csr<<<(N + 3) / 4, 256, 0, stream>>>(x, src_s, w_s, row_ptr, g, N);
    {
        dim3 grid((N + 127) / 128, 128 / 128);
        gemm_bias_relu<128><<<grid, 256, 0, stream>>>(g, W1, b1, h, N);
    }

    // ---- layer 2: out = relu((A @ h) @ W2 + b2) ----
    spmm_csr<<<(N + 3) / 4, 256, 0, stream>>>(h, src_s, w_s, row_ptr, g, N);
    {
        dim3 grid((N + 127) / 128, 256 / 128);
        gemm_bias_relu<256><<<grid, 256, 0, stream>>>(g, W2, b2, (float*)d_out, N);
    }
}

// Round 5
// 365.224 us; speedup vs baseline: 2.8719x; 1.6330x over previous
//
#include <hip/hip_runtime.h>
#include <hip/hip_bf16.h>

#define NHID 128

typedef __attribute__((ext_vector_type(8))) short short8v;
typedef __attribute__((ext_vector_type(4))) float f32x4;

__device__ __forceinline__ unsigned short f32_to_bf16(float f) {
    unsigned u = __float_as_uint(f);
    u += 0x7fffu + ((u >> 16) & 1u);   // round-to-nearest-even
    return (unsigned short)(u >> 16);
}

// ---------------- CSR build ----------------
__global__ void hist_kernel(const int* __restrict__ dst, int E, int* __restrict__ counts) {
    for (int e = blockIdx.x * blockDim.x + threadIdx.x; e < E; e += gridDim.x * blockDim.x)
        atomicAdd(&counts[dst[e]], 1);
}

__global__ __launch_bounds__(256) void block_sum_kernel(const int* __restrict__ counts, int n,
                                                        int* __restrict__ bsums) {
    __shared__ int red[256];
    int tid = threadIdx.x;
    int base = blockIdx.x * 2048 + tid * 8;
    int s = 0;
#pragma unroll
    for (int i = 0; i < 8; ++i) {
        int idx = base + i;
        if (idx < n) s += counts[idx];
    }
    red[tid] = s;
    __syncthreads();
    for (int off = 128; off > 0; off >>= 1) {
        if (tid < off) red[tid] += red[tid + off];
        __syncthreads();
    }
    if (tid == 0) bsums[blockIdx.x] = red[0];
}

__global__ void scan_bsums_kernel(const int* __restrict__ bsums, int nb, int* __restrict__ boffs) {
    int lane = threadIdx.x;  // 64 threads
    int orig = (lane < nb) ? bsums[lane] : 0;
    int v = orig;
#pragma unroll
    for (int off = 1; off < 64; off <<= 1) {
        int u = __shfl_up(v, off, 64);
        if (lane >= off) v += u;
    }
    if (lane < nb) boffs[lane] = v - orig;
    if (lane == 63) boffs[nb] = v;
}

__global__ __launch_bounds__(256) void scan_write_kernel(const int* __restrict__ counts, int n,
                                                         const int* __restrict__ boffs, int nb,
                                                         int* __restrict__ row_ptr,
                                                         int* __restrict__ cursor) {
    __shared__ int wsum[4];
    int tid = threadIdx.x;
    int lane = tid & 63;
    int wv = tid >> 6;
    int base = blockIdx.x * 2048 + tid * 8;

    int v[8];
    int s = 0;
#pragma unroll
    for (int i = 0; i < 8; ++i) {
        int idx = base + i;
        v[i] = (idx < n) ? counts[idx] : 0;
        s += v[i];
    }
    int incl = s;
#pragma unroll
    for (int off = 1; off < 64; off <<= 1) {
        int u = __shfl_up(incl, off, 64);
        if (lane >= off) incl += u;
    }
    if (lane == 63) wsum[wv] = incl;
    __syncthreads();
    int wexcl = 0;
    for (int w = 0; w < wv; ++w) wexcl += wsum[w];

    int run = boffs[blockIdx.x] + wexcl + (incl - s);
#pragma unroll
    for (int i = 0; i < 8; ++i) {
        int idx = base + i;
        if (idx < n) {
            row_ptr[idx] = run;
            cursor[idx] = run;
        }
        run += v[i];
    }
    if (blockIdx.x == 0 && tid == 0) row_ptr[n] = boffs[nb];
}

__global__ void scatter_kernel(const int* __restrict__ src, const int* __restrict__ dst,
                               const float* __restrict__ w, int E,
                               int* __restrict__ cursor, int* __restrict__ src_s,
                               float* __restrict__ w_s) {
    for (int e = blockIdx.x * blockDim.x + threadIdx.x; e < E; e += gridDim.x * blockDim.x) {
        int d = dst[e];
        int pos = atomicAdd(&cursor[d], 1);
        src_s[pos] = src[e];
        w_s[pos] = w[e];
    }
}

// ---------------- converts ----------------
__global__ void convert_f32_bf16(const float* __restrict__ x, unsigned short* __restrict__ xb,
                                 size_t n4) {
    size_t stride = (size_t)gridDim.x * blockDim.x;
    for (size_t i = (size_t)blockIdx.x * blockDim.x + threadIdx.x; i < n4; i += stride) {
        float4 v = reinterpret_cast<const float4*>(x)[i];
        ushort4 o = make_ushort4(f32_to_bf16(v.x), f32_to_bf16(v.y), f32_to_bf16(v.z),
                                 f32_to_bf16(v.w));
        reinterpret_cast<ushort4*>(xb)[i] = o;
    }
}

// WT[n][k] = bf16(W[k][n]); grid (N/32, K/32), block 256
__global__ __launch_bounds__(256) void transpose_w_bf16(const float* __restrict__ W,
                                                        unsigned short* __restrict__ WT,
                                                        int K, int N) {
    __shared__ float t[32][33];
    int n0 = blockIdx.x * 32, k0 = blockIdx.y * 32;
    int tx = threadIdx.x & 31;
    int ty = threadIdx.x >> 5;  // 0..7
#pragma unroll
    for (int i = 0; i < 32; i += 8)
        t[ty + i][tx] = W[(size_t)(k0 + ty + i) * N + n0 + tx];
    __syncthreads();
#pragma unroll
    for (int i = 0; i < 32; i += 8)
        WT[(size_t)(n0 + ty + i) * K + k0 + tx] = f32_to_bf16(t[tx][ty + i]);
}

// ---------------- SpMM (bf16 rows): out[node] = bf16( sum_e w_e * X[src_e] ) ----------------
// One wave per node. Quarter-wave (16 lanes) per gathered row: lane q covers cols q*8..q*8+7
// (uint4 = 8 bf16). 4 rows per step, 4 steps unrolled -> 16 gather loads in flight per wave.
__global__ __launch_bounds__(256) void spmm_csr_bf16(const unsigned short* __restrict__ X,
                                                     const int* __restrict__ src_s,
                                                     const float* __restrict__ w_s,
                                                     const int* __restrict__ row_ptr,
                                                     unsigned short* __restrict__ out, int n) {
    int node = blockIdx.x * 4 + (threadIdx.x >> 6);
    if (node >= n) return;
    const int lane = threadIdx.x & 63;
    const int grp = lane >> 4;   // 0..3
    const int q = lane & 15;     // 16B chunk

    int beg = row_ptr[node];
    int end = row_ptr[node + 1];

    float acc[8];
#pragma unroll
    for (int j = 0; j < 8; ++j) acc[j] = 0.f;

    for (int e0 = beg; e0 < end; e0 += 64) {
        int cnt = min(64, end - e0);
        int s = 0;
        float ww = 0.f;
        if (lane < cnt) {
            s = src_s[e0 + lane];
            ww = w_s[e0 + lane];
        }

        int i = 0;
        for (; i + 16 <= cnt; i += 16) {
            int sx[4];
            float wx[4];
#pragma unroll
            for (int u = 0; u < 4; ++u) {
                sx[u] = __shfl(s, i + u * 4 + grp, 64);
                wx[u] = __shfl(ww, i + u * 4 + grp, 64);
            }
            uint4 v[4];
#pragma unroll
            for (int u = 0; u < 4; ++u)
                v[u] = *reinterpret_cast<const uint4*>(&X[(size_t)sx[u] * NHID + q * 8]);
#pragma unroll
            for (int u = 0; u < 4; ++u) {
                unsigned pw;
                pw = v[u].x;
                acc[0] += wx[u] * __uint_as_float(pw << 16);
                acc[1] += wx[u] * __uint_as_float(pw & 0xffff0000u);
                pw = v[u].y;
                acc[2] += wx[u] * __uint_as_float(pw << 16);
                acc[3] += wx[u] * __uint_as_float(pw & 0xffff0000u);
                pw = v[u].z;
                acc[4] += wx[u] * __uint_as_float(pw << 16);
                acc[5] += wx[u] * __uint_as_float(pw & 0xffff0000u);
                pw = v[u].w;
                acc[6] += wx[u] * __uint_as_float(pw << 16);
                acc[7] += wx[u] * __uint_as_float(pw & 0xffff0000u);
            }
        }
        for (; i + 4 <= cnt; i += 4) {
            int sx = __shfl(s, i + grp, 64);
            float wx = __shfl(ww, i + grp, 64);
            uint4 v = *reinterpret_cast<const uint4*>(&X[(size_t)sx * NHID + q * 8]);
            unsigned pw;
            pw = v.x;
            acc[0] += wx * __uint_as_float(pw << 16);
            acc[1] += wx * __uint_as_float(pw & 0xffff0000u);
            pw = v.y;
            acc[2] += wx * __uint_as_float(pw << 16);
            acc[3] += wx * __uint_as_float(pw & 0xffff0000u);
            pw = v.z;
            acc[4] += wx * __uint_as_float(pw << 16);
            acc[5] += wx * __uint_as_float(pw & 0xffff0000u);
            pw = v.w;
            acc[6] += wx * __uint_as_float(pw << 16);
            acc[7] += wx * __uint_as_float(pw & 0xffff0000u);
        }
        if (i < cnt) {
            int idx = i + grp;
            int sx = __shfl(s, idx, 64);
            float wx = __shfl(ww, idx, 64);
            if (idx < cnt) {
                uint4 v = *reinterpret_cast<const uint4*>(&X[(size_t)sx * NHID + q * 8]);
                unsigned pw;
                pw = v.x;
                acc[0] += wx * __uint_as_float(pw << 16);
                acc[1] += wx * __uint_as_float(pw & 0xffff0000u);
                pw = v.y;
                acc[2] += wx * __uint_as_float(pw << 16);
                acc[3] += wx * __uint_as_float(pw & 0xffff0000u);
                pw = v.z;
                acc[4] += wx * __uint_as_float(pw << 16);
                acc[5] += wx * __uint_as_float(pw & 0xffff0000u);
                pw = v.w;
                acc[6] += wx * __uint_as_float(pw << 16);
                acc[7] += wx * __uint_as_float(pw & 0xffff0000u);
            }
        }
    }

    // reduce the 4 quarter-wave partial sums
#pragma unroll
    for (int j = 0; j < 8; ++j) {
        acc[j] += __shfl_xor(acc[j], 16, 64);
        acc[j] += __shfl_xor(acc[j], 32, 64);
    }

    if (grp == 0) {
        short8v o;
#pragma unroll
        for (int j = 0; j < 8; ++j) o[j] = (short)f32_to_bf16(acc[j]);
        *reinterpret_cast<short8v*>(&out[(size_t)node * NHID + q * 8]) = o;
    }
}

// ---------------- MFMA GEMM + bias + ReLU ----------------
// out = relu(Xb[nrows,128](bf16) @ W[128,DOUT](bf16, given transposed WT[DOUT][128]) + b)
// 128x128 tile, 4 waves in 2x2, each wave 64x64 via 16 x mfma_f32_16x16x32_bf16 per K-step.
// LDS XOR-swizzle: chunk c16' = c16 ^ (row & 15) -> 2-way bank access (free).
template <int DOUT, bool OUT_BF16>
__global__ __launch_bounds__(256) void gemm_mfma(const unsigned short* __restrict__ Xb,
                                                 const unsigned short* __restrict__ WT,
                                                 const float* __restrict__ bias,
                                                 void* __restrict__ outv, int nrows) {
    __shared__ unsigned short Ab[128 * 128];
    __shared__ unsigned short Bb[128 * 128];
    const int row0 = blockIdx.x * 128;
    const int col0 = blockIdx.y * 128;
    const int tid = threadIdx.x;
    const int lane = tid & 63;
    const int wid = tid >> 6;
    const int waveM = wid >> 1;
    const int waveN = wid & 1;

    // stage A (Xb rows) and B (WT rows), both [128 rows][128 k] bf16, swizzled
    {
        const int c = tid & 15;
        int r = tid >> 4;
#pragma unroll
        for (int p = 0; p < 8; ++p, r += 16) {
            int row = row0 + r;
            uint4 va = make_uint4(0, 0, 0, 0);
            if (row < nrows) va = *reinterpret_cast<const uint4*>(&Xb[(size_t)row * 128 + c * 8]);
            uint4 vb = *reinterpret_cast<const uint4*>(&WT[(size_t)(col0 + r) * 128 + c * 8]);
            int cs = (c ^ (r & 15)) * 8;
            *reinterpret_cast<uint4*>(&Ab[r * 128 + cs]) = va;
            *reinterpret_cast<uint4*>(&Bb[r * 128 + cs]) = vb;
        }
    }
    __syncthreads();

    const int lr = lane & 15;
    const int lk = lane >> 4;  // 0..3

    f32x4 acc[4][4];
#pragma unroll
    for (int m = 0; m < 4; ++m)
#pragma unroll
        for (int nn = 0; nn < 4; ++nn) acc[m][nn] = (f32x4){0.f, 0.f, 0.f, 0.f};

#pragma unroll
    for (int ks = 0; ks < 4; ++ks) {
        short8v a[4], b[4];
#pragma unroll
        for (int m = 0; m < 4; ++m) {
            int row = waveM * 64 + m * 16 + lr;
            int c16 = (ks * 4 + lk) ^ (row & 15);
            a[m] = *reinterpret_cast<const short8v*>(&Ab[row * 128 + c16 * 8]);
        }
#pragma unroll
        for (int nn = 0; nn < 4; ++nn) {
            int rowb = waveN * 64 + nn * 16 + lr;
            int c16 = (ks * 4 + lk) ^ (rowb & 15);
            b[nn] = *reinterpret_cast<const short8v*>(&Bb[rowb * 128 + c16 * 8]);
        }
#pragma unroll
        for (int m = 0; m < 4; ++m)
#pragma unroll
            for (int nn = 0; nn < 4; ++nn)
                acc[m][nn] = __builtin_amdgcn_mfma_f32_16x16x32_bf16(a[m], b[nn], acc[m][nn], 0, 0, 0);
    }

    float bj[4];
#pragma unroll
    for (int nn = 0; nn < 4; ++nn) bj[nn] = bias[col0 + waveN * 64 + nn * 16 + lr];

#pragma unroll
    for (int m = 0; m < 4; ++m) {
        int rbase = row0 + waveM * 64 + m * 16 + lk * 4;
#pragma unroll
        for (int reg = 0; reg < 4; ++reg) {
            int r = rbase + reg;
            if (r >= nrows) continue;
#pragma unroll
            for (int nn = 0; nn < 4; ++nn) {
                int cidx = col0 + waveN * 64 + nn * 16 + lr;
                float v = fmaxf(acc[m][nn][reg] + bj[nn], 0.f);
                if (OUT_BF16)
                    ((unsigned short*)outv)[(size_t)r * DOUT + cidx] = f32_to_bf16(v);
                else
                    ((float*)outv)[(size_t)r * DOUT + cidx] = v;
            }
        }
    }
}

extern "C" void kernel_launch(void* const* d_in, const int* in_sizes, int n_in,
                              void* d_out, int out_size, void* d_ws, size_t ws_size,
                              hipStream_t stream) {
    const float* x  = (const float*)d_in[0];
    const float* ew = (const float*)d_in[1];
    const float* W1 = (const float*)d_in[2];
    const float* b1 = (const float*)d_in[3];
    const float* W2 = (const float*)d_in[4];
    const float* b2 = (const float*)d_in[5];
    const int*   ei = (const int*)d_in[6];

    const int N = in_sizes[0] / NHID;   // 100000
    const int E = in_sizes[1];          // 1600000
    const int* src = ei;
    const int* dst = ei + E;

    auto align256 = [](size_t v) { return (v + 255) & ~(size_t)255; };
    char* p = (char*)d_ws;
    unsigned short* xb  = (unsigned short*)p; p += align256((size_t)N * NHID * 2);
    unsigned short* gb  = (unsigned short*)p; p += align256((size_t)N * NHID * 2);
    unsigned short* hb  = (unsigned short*)p; p += align256((size_t)N * NHID * 2);
    unsigned short* W1T = (unsigned short*)p; p += align256((size_t)128 * 128 * 2);
    unsigned short* W2T = (unsigned short*)p; p += align256((size_t)256 * 128 * 2);
    int*   counts  = (int*)p;   p += align256((size_t)N * 4);
    int*   row_ptr = (int*)p;   p += align256((size_t)(N + 1) * 4);
    int*   cursor  = (int*)p;   p += align256((size_t)N * 4);
    int*   src_s   = (int*)p;   p += align256((size_t)E * 4);
    float* w_s     = (float*)p; p += align256((size_t)E * 4);
    int*   bsums   = (int*)p;   p += align256((size_t)128 * 4);
    int*   boffs   = (int*)p;   p += align256((size_t)128 * 4);

    const int nb = (N + 2047) / 2048;   // 49 for N=100000

    // ---- CSR build ----
    hipMemsetAsync(counts, 0, (size_t)N * 4, stream);
    hist_kernel<<<2048, 256, 0, stream>>>(dst, E, counts);
    block_sum_kernel<<<nb, 256, 0, stream>>>(counts, N, bsums);
    scan_bsums_kernel<<<1, 64, 0, stream>>>(bsums, nb, boffs);
    scan_write_kernel<<<nb, 256, 0, stream>>>(counts, N, boffs, nb, row_ptr, cursor);
    scatter_kernel<<<2048, 256, 0, stream>>>(src, dst, ew, E, cursor, src_s, w_s);

    // ---- precision converts ----
    convert_f32_bf16<<<2048, 256, 0, stream>>>(x, xb, (size_t)N * NHID / 4);
    {
        dim3 g1(128 / 32, 128 / 32);
        transpose_w_bf16<<<g1, 256, 0, stream>>>(W1, W1T, 128, 128);
        dim3 g2(256 / 32, 128 / 32);
        transpose_w_bf16<<<g2, 256, 0, stream>>>(W2, W2T, 128, 256);
    }

    // ---- layer 1: h = relu((A @ x) @ W1 + b1) ----
    spmm_csr_bf16<<<(N + 3) / 4, 256, 0, stream>>>(xb, src_s, w_s, row_ptr, gb, N);
    {
        dim3 grid((N + 127) / 128, 1);
        gemm_mfma<128, true><<<grid, 256, 0, stream>>>(gb, W1T, b1, hb, N);
    }

    // ---- layer 2: out = relu((A @ h) @ W2 + b2) ----
    spmm_csr_bf16<<<(N + 3) / 4, 256, 0, stream>>>(hb, src_s, w_s, row_ptr, gb, N);
    {
        dim3 grid((N + 127) / 128, 2);
        gemm_mfma<256, false><<<grid, 256, 0, stream>>>(gb, W2T, b2, (float*)d_out, N);
    }
}

// Round 6
// 280.015 us; speedup vs baseline: 3.7458x; 1.3043x over previous
//
#include <hip/hip_runtime.h>
#include <hip/hip_bf16.h>

#define NHID 128
#define NBLK 128     // blocks for coarse hist / partition
#define FCAP 4096    // LDS stash capacity (edges) in fine kernel

typedef __attribute__((ext_vector_type(8))) short short8v;
typedef __attribute__((ext_vector_type(4))) float f32x4;

__device__ __forceinline__ unsigned short f32_to_bf16(float f) {
    unsigned u = __float_as_uint(f);
    u += 0x7fffu + ((u >> 16) & 1u);   // round-to-nearest-even
    return (unsigned short)(u >> 16);
}

// ---------------- two-level CSR build ----------------
// bucket = dst >> 7 (128 nodes per bucket). Packing: src (<=2^17) | dst_low7 << 17.

__global__ __launch_bounds__(256) void coarse_hist_kernel(const int* __restrict__ dst, int E,
                                                          int nbuck, int* __restrict__ ghist) {
    __shared__ int h[1024];
    for (int i = threadIdx.x; i < nbuck; i += 256) h[i] = 0;
    __syncthreads();
    int per = (E + NBLK - 1) / NBLK;
    int b0 = blockIdx.x * per;
    int b1 = min(E, b0 + per);
    for (int e = b0 + threadIdx.x; e < b1; e += 256)
        atomicAdd(&h[dst[e] >> 7], 1);
    __syncthreads();
    for (int i = threadIdx.x; i < nbuck; i += 256)
        ghist[(size_t)i * NBLK + blockIdx.x] = h[i];
}

// ---- 3-kernel device-wide exclusive scan over counts[n] -> out (+ out[n]=total) ----
__global__ __launch_bounds__(256) void block_sum_kernel(const int* __restrict__ counts, int n,
                                                        int* __restrict__ bsums) {
    __shared__ int red[256];
    int tid = threadIdx.x;
    int base = blockIdx.x * 2048 + tid * 8;
    int s = 0;
#pragma unroll
    for (int i = 0; i < 8; ++i) {
        int idx = base + i;
        if (idx < n) s += counts[idx];
    }
    red[tid] = s;
    __syncthreads();
    for (int off = 128; off > 0; off >>= 1) {
        if (tid < off) red[tid] += red[tid + off];
        __syncthreads();
    }
    if (tid == 0) bsums[blockIdx.x] = red[0];
}

__global__ void scan_bsums_kernel(const int* __restrict__ bsums, int nb, int* __restrict__ boffs) {
    int lane = threadIdx.x;  // 64 threads
    int orig = (lane < nb) ? bsums[lane] : 0;
    int v = orig;
#pragma unroll
    for (int off = 1; off < 64; off <<= 1) {
        int u = __shfl_up(v, off, 64);
        if (lane >= off) v += u;
    }
    if (lane < nb) boffs[lane] = v - orig;
    if (lane == 63) boffs[nb] = v;
}

__global__ __launch_bounds__(256) void scan_write_kernel(const int* __restrict__ counts, int n,
                                                         const int* __restrict__ boffs, int nb,
                                                         int* __restrict__ out) {
    __shared__ int wsum[4];
    int tid = threadIdx.x;
    int lane = tid & 63;
    int wv = tid >> 6;
    int base = blockIdx.x * 2048 + tid * 8;

    int v[8];
    int s = 0;
#pragma unroll
    for (int i = 0; i < 8; ++i) {
        int idx = base + i;
        v[i] = (idx < n) ? counts[idx] : 0;
        s += v[i];
    }
    int incl = s;
#pragma unroll
    for (int off = 1; off < 64; off <<= 1) {
        int u = __shfl_up(incl, off, 64);
        if (lane >= off) incl += u;
    }
    if (lane == 63) wsum[wv] = incl;
    __syncthreads();
    int wexcl = 0;
    for (int w = 0; w < wv; ++w) wexcl += wsum[w];

    int run = boffs[blockIdx.x] + wexcl + (incl - s);
#pragma unroll
    for (int i = 0; i < 8; ++i) {
        int idx = base + i;
        if (idx < n) out[idx] = run;
        run += v[i];
    }
    if (blockIdx.x == 0 && tid == 0) out[n] = boffs[nb];
}

__global__ __launch_bounds__(256) void partition_kernel(const int* __restrict__ src,
                                                        const int* __restrict__ dst,
                                                        const float* __restrict__ w, int E,
                                                        int nbuck, const int* __restrict__ gofs,
                                                        uint2* __restrict__ coarse) {
    __shared__ int cur[1024];
    for (int i = threadIdx.x; i < nbuck; i += 256)
        cur[i] = gofs[(size_t)i * NBLK + blockIdx.x];
    __syncthreads();
    int per = (E + NBLK - 1) / NBLK;
    int b0 = blockIdx.x * per;
    int b1 = min(E, b0 + per);
    for (int e = b0 + threadIdx.x; e < b1; e += 256) {
        int d = dst[e];
        int bk = d >> 7;
        int pos = atomicAdd(&cur[bk], 1);
        uint2 pk;
        pk.x = (unsigned)src[e] | ((unsigned)(d & 127) << 17);
        pk.y = __float_as_uint(w[e]);
        coarse[pos] = pk;
    }
}

// One workgroup per bucket: build exact per-node CSR for its 128 nodes.
__global__ __launch_bounds__(256) void fine_kernel(const uint2* __restrict__ coarse,
                                                   const int* __restrict__ gofs, int N, int E,
                                                   int* __restrict__ row_ptr,
                                                   int* __restrict__ src_s,
                                                   float* __restrict__ w_s) {
    __shared__ uint2 stash[FCAP];
    __shared__ int hist[128];
    __shared__ int excl[128];
    int b = blockIdx.x;
    int gstart = gofs[(size_t)b * NBLK];
    int gend = gofs[(size_t)(b + 1) * NBLK];
    int cnt = gend - gstart;
    int tid = threadIdx.x;
    if (tid < 128) hist[tid] = 0;
    __syncthreads();
    for (int i = tid; i < cnt; i += 256) {
        uint2 e = coarse[gstart + i];
        if (i < FCAP) stash[i] = e;
        atomicAdd(&hist[(e.x >> 17) & 127], 1);
    }
    __syncthreads();
    // exclusive scan of hist[0..127] by wave 0
    if (tid < 64) {
        int a = hist[tid];
        int c = hist[tid + 64];
        int ia = a, ic = c;
#pragma unroll
        for (int off = 1; off < 64; off <<= 1) {
            int u = __shfl_up(ia, off, 64);
            if (tid >= off) ia += u;
            u = __shfl_up(ic, off, 64);
            if (tid >= off) ic += u;
        }
        int totA = __shfl(ia, 63, 64);
        excl[tid] = ia - a;
        excl[tid + 64] = totA + ic - c;
    }
    __syncthreads();
    int node0 = b << 7;
    if (tid < 128 && node0 + tid < N) row_ptr[node0 + tid] = gstart + excl[tid];
    if (b == 0 && tid == 0) row_ptr[N] = E;
    if (tid < 128) hist[tid] = excl[tid];   // reuse as cursor
    __syncthreads();
    for (int i = tid; i < cnt; i += 256) {
        uint2 e = (i < FCAP) ? stash[i] : coarse[gstart + i];
        int dl = (e.x >> 17) & 127;
        int pos = atomicAdd(&hist[dl], 1);
        src_s[gstart + pos] = (int)(e.x & 0x1FFFFu);
        w_s[gstart + pos] = __uint_as_float(e.y);
    }
}

// ---------------- converts ----------------
__global__ void convert_f32_bf16(const float* __restrict__ x, unsigned short* __restrict__ xb,
                                 size_t n4) {
    size_t stride = (size_t)gridDim.x * blockDim.x;
    for (size_t i = (size_t)blockIdx.x * blockDim.x + threadIdx.x; i < n4; i += stride) {
        float4 v = reinterpret_cast<const float4*>(x)[i];
        ushort4 o = make_ushort4(f32_to_bf16(v.x), f32_to_bf16(v.y), f32_to_bf16(v.z),
                                 f32_to_bf16(v.w));
        reinterpret_cast<ushort4*>(xb)[i] = o;
    }
}

// WT[n][k] = bf16(W[k][n]); grid (N/32, K/32), block 256
__global__ __launch_bounds__(256) void transpose_w_bf16(const float* __restrict__ W,
                                                        unsigned short* __restrict__ WT,
                                                        int K, int N) {
    __shared__ float t[32][33];
    int n0 = blockIdx.x * 32, k0 = blockIdx.y * 32;
    int tx = threadIdx.x & 31;
    int ty = threadIdx.x >> 5;  // 0..7
#pragma unroll
    for (int i = 0; i < 32; i += 8)
        t[ty + i][tx] = W[(size_t)(k0 + ty + i) * N + n0 + tx];
    __syncthreads();
#pragma unroll
    for (int i = 0; i < 32; i += 8)
        WT[(size_t)(n0 + ty + i) * K + k0 + tx] = f32_to_bf16(t[tx][ty + i]);
}

// ---------------- SpMM (bf16 rows): out[node] = bf16( sum_e w_e * X[src_e] ) ----------------
__global__ __launch_bounds__(256) void spmm_csr_bf16(const unsigned short* __restrict__ X,
                                                     const int* __restrict__ src_s,
                                                     const float* __restrict__ w_s,
                                                     const int* __restrict__ row_ptr,
                                                     unsigned short* __restrict__ out, int n) {
    int node = blockIdx.x * 4 + (threadIdx.x >> 6);
    if (node >= n) return;
    const int lane = threadIdx.x & 63;
    const int grp = lane >> 4;   // 0..3
    const int q = lane & 15;     // 16B chunk

    int beg = row_ptr[node];
    int end = row_ptr[node + 1];

    float acc[8];
#pragma unroll
    for (int j = 0; j < 8; ++j) acc[j] = 0.f;

    for (int e0 = beg; e0 < end; e0 += 64) {
        int cnt = min(64, end - e0);
        int s = 0;
        float ww = 0.f;
        if (lane < cnt) {
            s = src_s[e0 + lane];
            ww = w_s[e0 + lane];
        }

        int i = 0;
        for (; i + 16 <= cnt; i += 16) {
            int sx[4];
            float wx[4];
#pragma unroll
            for (int u = 0; u < 4; ++u) {
                sx[u] = __shfl(s, i + u * 4 + grp, 64);
                wx[u] = __shfl(ww, i + u * 4 + grp, 64);
            }
            uint4 v[4];
#pragma unroll
            for (int u = 0; u < 4; ++u)
                v[u] = *reinterpret_cast<const uint4*>(&X[(size_t)sx[u] * NHID + q * 8]);
#pragma unroll
            for (int u = 0; u < 4; ++u) {
                unsigned pw;
                pw = v[u].x;
                acc[0] += wx[u] * __uint_as_float(pw << 16);
                acc[1] += wx[u] * __uint_as_float(pw & 0xffff0000u);
                pw = v[u].y;
                acc[2] += wx[u] * __uint_as_float(pw << 16);
                acc[3] += wx[u] * __uint_as_float(pw & 0xffff0000u);
                pw = v[u].z;
                acc[4] += wx[u] * __uint_as_float(pw << 16);
                acc[5] += wx[u] * __uint_as_float(pw & 0xffff0000u);
                pw = v[u].w;
                acc[6] += wx[u] * __uint_as_float(pw << 16);
                acc[7] += wx[u] * __uint_as_float(pw & 0xffff0000u);
            }
        }
        for (; i + 4 <= cnt; i += 4) {
            int sx = __shfl(s, i + grp, 64);
            float wx = __shfl(ww, i + grp, 64);
            uint4 v = *reinterpret_cast<const uint4*>(&X[(size_t)sx * NHID + q * 8]);
            unsigned pw;
            pw = v.x;
            acc[0] += wx * __uint_as_float(pw << 16);
            acc[1] += wx * __uint_as_float(pw & 0xffff0000u);
            pw = v.y;
            acc[2] += wx * __uint_as_float(pw << 16);
            acc[3] += wx * __uint_as_float(pw & 0xffff0000u);
            pw = v.z;
            acc[4] += wx * __uint_as_float(pw << 16);
            acc[5] += wx * __uint_as_float(pw & 0xffff0000u);
            pw = v.w;
            acc[6] += wx * __uint_as_float(pw << 16);
            acc[7] += wx * __uint_as_float(pw & 0xffff0000u);
        }
        if (i < cnt) {
            int idx = i + grp;
            int sx = __shfl(s, idx, 64);
            float wx = __shfl(ww, idx, 64);
            if (idx < cnt) {
                uint4 v = *reinterpret_cast<const uint4*>(&X[(size_t)sx * NHID + q * 8]);
                unsigned pw;
                pw = v.x;
                acc[0] += wx * __uint_as_float(pw << 16);
                acc[1] += wx * __uint_as_float(pw & 0xffff0000u);
                pw = v.y;
                acc[2] += wx * __uint_as_float(pw << 16);
                acc[3] += wx * __uint_as_float(pw & 0xffff0000u);
                pw = v.z;
                acc[4] += wx * __uint_as_float(pw << 16);
                acc[5] += wx * __uint_as_float(pw & 0xffff0000u);
                pw = v.w;
                acc[6] += wx * __uint_as_float(pw << 16);
                acc[7] += wx * __uint_as_float(pw & 0xffff0000u);
            }
        }
    }

#pragma unroll
    for (int j = 0; j < 8; ++j) {
        acc[j] += __shfl_xor(acc[j], 16, 64);
        acc[j] += __shfl_xor(acc[j], 32, 64);
    }

    if (grp == 0) {
        short8v o;
#pragma unroll
        for (int j = 0; j < 8; ++j) o[j] = (short)f32_to_bf16(acc[j]);
        *reinterpret_cast<short8v*>(&out[(size_t)node * NHID + q * 8]) = o;
    }
}

// ---------------- MFMA GEMM + bias + ReLU ----------------
template <int DOUT, bool OUT_BF16>
__global__ __launch_bounds__(256) void gemm_mfma(const unsigned short* __restrict__ Xb,
                                                 const unsigned short* __restrict__ WT,
                                                 const float* __restrict__ bias,
                                                 void* __restrict__ outv, int nrows) {
    __shared__ unsigned short Ab[128 * 128];
    __shared__ unsigned short Bb[128 * 128];
    const int row0 = blockIdx.x * 128;
    const int col0 = blockIdx.y * 128;
    const int tid = threadIdx.x;
    const int lane = tid & 63;
    const int wid = tid >> 6;
    const int waveM = wid >> 1;
    const int waveN = wid & 1;

    {
        const int c = tid & 15;
        int r = tid >> 4;
#pragma unroll
        for (int p = 0; p < 8; ++p, r += 16) {
            int row = row0 + r;
            uint4 va = make_uint4(0, 0, 0, 0);
            if (row < nrows) va = *reinterpret_cast<const uint4*>(&Xb[(size_t)row * 128 + c * 8]);
            uint4 vb = *reinterpret_cast<const uint4*>(&WT[(size_t)(col0 + r) * 128 + c * 8]);
            int cs = (c ^ (r & 15)) * 8;
            *reinterpret_cast<uint4*>(&Ab[r * 128 + cs]) = va;
            *reinterpret_cast<uint4*>(&Bb[r * 128 + cs]) = vb;
        }
    }
    __syncthreads();

    const int lr = lane & 15;
    const int lk = lane >> 4;

    f32x4 acc[4][4];
#pragma unroll
    for (int m = 0; m < 4; ++m)
#pragma unroll
        for (int nn = 0; nn < 4; ++nn) acc[m][nn] = (f32x4){0.f, 0.f, 0.f, 0.f};

#pragma unroll
    for (int ks = 0; ks < 4; ++ks) {
        short8v a[4], b[4];
#pragma unroll
        for (int m = 0; m < 4; ++m) {
            int row = waveM * 64 + m * 16 + lr;
            int c16 = (ks * 4 + lk) ^ (row & 15);
            a[m] = *reinterpret_cast<const short8v*>(&Ab[row * 128 + c16 * 8]);
        }
#pragma unroll
        for (int nn = 0; nn < 4; ++nn) {
            int rowb = waveN * 64 + nn * 16 + lr;
            int c16 = (ks * 4 + lk) ^ (rowb & 15);
            b[nn] = *reinterpret_cast<const short8v*>(&Bb[rowb * 128 + c16 * 8]);
        }
#pragma unroll
        for (int m = 0; m < 4; ++m)
#pragma unroll
            for (int nn = 0; nn < 4; ++nn)
                acc[m][nn] = __builtin_amdgcn_mfma_f32_16x16x32_bf16(a[m], b[nn], acc[m][nn], 0, 0, 0);
    }

    float bj[4];
#pragma unroll
    for (int nn = 0; nn < 4; ++nn) bj[nn] = bias[col0 + waveN * 64 + nn * 16 + lr];

#pragma unroll
    for (int m = 0; m < 4; ++m) {
        int rbase = row0 + waveM * 64 + m * 16 + lk * 4;
#pragma unroll
        for (int reg = 0; reg < 4; ++reg) {
            int r = rbase + reg;
            if (r >= nrows) continue;
#pragma unroll
            for (int nn = 0; nn < 4; ++nn) {
                int cidx = col0 + waveN * 64 + nn * 16 + lr;
                float v = fmaxf(acc[m][nn][reg] + bj[nn], 0.f);
                if (OUT_BF16)
                    ((unsigned short*)outv)[(size_t)r * DOUT + cidx] = f32_to_bf16(v);
                else
                    ((float*)outv)[(size_t)r * DOUT + cidx] = v;
            }
        }
    }
}

extern "C" void kernel_launch(void* const* d_in, const int* in_sizes, int n_in,
                              void* d_out, int out_size, void* d_ws, size_t ws_size,
                              hipStream_t stream) {
    const float* x  = (const float*)d_in[0];
    const float* ew = (const float*)d_in[1];
    const float* W1 = (const float*)d_in[2];
    const float* b1 = (const float*)d_in[3];
    const float* W2 = (const float*)d_in[4];
    const float* b2 = (const float*)d_in[5];
    const int*   ei = (const int*)d_in[6];

    const int N = in_sizes[0] / NHID;   // 100000 (must be < 131072 for 17-bit src packing)
    const int E = in_sizes[1];          // 1600000
    const int* src = ei;
    const int* dst = ei + E;

    const int nbuck = (N + 127) >> 7;           // 782
    const int n2 = nbuck * NBLK;                // 100096 scan elements
    const int nb2 = (n2 + 2047) / 2048;         // 49 (<=64)

    auto align256 = [](size_t v) { return (v + 255) & ~(size_t)255; };
    char* p = (char*)d_ws;
    unsigned short* xb  = (unsigned short*)p; p += align256((size_t)N * NHID * 2);
    unsigned short* gb  = (unsigned short*)p; p += align256((size_t)N * NHID * 2);
    unsigned short* hb  = (unsigned short*)p; p += align256((size_t)N * NHID * 2);
    unsigned short* W1T = (unsigned short*)p; p += align256((size_t)128 * 128 * 2);
    unsigned short* W2T = (unsigned short*)p; p += align256((size_t)256 * 128 * 2);
    int*   ghist   = (int*)p;   p += align256((size_t)(n2 + 1) * 4);
    int*   gofs    = (int*)p;   p += align256((size_t)(n2 + 1) * 4);
    int*   row_ptr = (int*)p;   p += align256((size_t)(N + 1) * 4);
    int*   src_s   = (int*)p;   p += align256((size_t)E * 4);
    float* w_s     = (float*)p; p += align256((size_t)E * 4);
    uint2* coarse  = (uint2*)p; p += align256((size_t)E * 8);
    int*   bsums   = (int*)p;   p += align256((size_t)128 * 4);
    int*   boffs   = (int*)p;   p += align256((size_t)128 * 4);

    // ---- CSR build: coarse hist -> scan -> partition -> fine ----
    coarse_hist_kernel<<<NBLK, 256, 0, stream>>>(dst, E, nbuck, ghist);
    block_sum_kernel<<<nb2, 256, 0, stream>>>(ghist, n2, bsums);
    scan_bsums_kernel<<<1, 64, 0, stream>>>(bsums, nb2, boffs);
    scan_write_kernel<<<nb2, 256, 0, stream>>>(ghist, n2, boffs, nb2, gofs);
    partition_kernel<<<NBLK, 256, 0, stream>>>(src, dst, ew, E, nbuck, gofs, coarse);
    fine_kernel<<<nbuck, 256, 0, stream>>>(coarse, gofs, N, E, row_ptr, src_s, w_s);

    // ---- precision converts ----
    convert_f32_bf16<<<2048, 256, 0, stream>>>(x, xb, (size_t)N * NHID / 4);
    {
        dim3 g1(128 / 32, 128 / 32);
        transpose_w_bf16<<<g1, 256, 0, stream>>>(W1, W1T, 128, 128);
        dim3 g2(256 / 32, 128 / 32);
        transpose_w_bf16<<<g2, 256, 0, stream>>>(W2, W2T, 128, 256);
    }

    // ---- layer 1: h = relu((A @ x) @ W1 + b1) ----
    spmm_csr_bf16<<<(N + 3) / 4, 256, 0, stream>>>(xb, src_s, w_s, row_ptr, gb, N);
    {
        dim3 grid((N + 127) / 128, 1);
        gemm_mfma<128, true><<<grid, 256, 0, stream>>>(gb, W1T, b1, hb, N);
    }

    // ---- layer 2: out = relu((A @ h) @ W2 + b2) ----
    spmm_csr_bf16<<<(N + 3) / 4, 256, 0, stream>>>(hb, src_s, w_s, row_ptr, gb, N);
    {
        dim3 grid((N + 127) / 128, 2);
        gemm_mfma<256, false><<<grid, 256, 0, stream>>>(gb, W2T, b2, (float*)d_out, N);
    }
}

// Round 7
// 251.566 us; speedup vs baseline: 4.1694x; 1.1131x over previous
//
#include <hip/hip_runtime.h>
#include <hip/hip_bf16.h>

#define NHID 128
#define NBLK 512     // blocks for coarse hist / partition
#define FCAP 4096    // LDS stash capacity (edges) in fine kernel

typedef __attribute__((ext_vector_type(8))) short short8v;
typedef __attribute__((ext_vector_type(4))) float f32x4;

__device__ __forceinline__ unsigned short f32_to_bf16(float f) {
    unsigned u = __float_as_uint(f);
    u += 0x7fffu + ((u >> 16) & 1u);   // round-to-nearest-even
    return (unsigned short)(u >> 16);
}

// ---------------- two-level CSR build ----------------
// bucket = dst >> 7 (128 nodes per bucket). Packing: src (<=2^17) | dst_low7 << 17.

__global__ __launch_bounds__(256) void coarse_hist_kernel(const int* __restrict__ dst, int E,
                                                          int nbuck, int per,
                                                          int* __restrict__ ghist) {
    __shared__ int h[1024];
    for (int i = threadIdx.x; i < nbuck; i += 256) h[i] = 0;
    __syncthreads();
    int b0 = blockIdx.x * per;
    int b1 = min(E, b0 + per);
    int e = b0 + threadIdx.x * 4;
    for (; e + 4 <= b1; e += 1024) {
        int4 d4 = *reinterpret_cast<const int4*>(&dst[e]);
        atomicAdd(&h[d4.x >> 7], 1);
        atomicAdd(&h[d4.y >> 7], 1);
        atomicAdd(&h[d4.z >> 7], 1);
        atomicAdd(&h[d4.w >> 7], 1);
    }
    for (; e < b1; ++e) atomicAdd(&h[dst[e] >> 7], 1);
    __syncthreads();
    for (int i = threadIdx.x; i < nbuck; i += 256)
        ghist[(size_t)i * NBLK + blockIdx.x] = h[i];
}

// ---- 3-kernel device-wide exclusive scan over counts[n] -> out (+ out[n]=total) ----
__global__ __launch_bounds__(256) void block_sum_kernel(const int* __restrict__ counts, int n,
                                                        int* __restrict__ bsums) {
    __shared__ int red[256];
    int tid = threadIdx.x;
    int base = blockIdx.x * 2048 + tid * 8;
    int s = 0;
#pragma unroll
    for (int i = 0; i < 8; ++i) {
        int idx = base + i;
        if (idx < n) s += counts[idx];
    }
    red[tid] = s;
    __syncthreads();
    for (int off = 128; off > 0; off >>= 1) {
        if (tid < off) red[tid] += red[tid + off];
        __syncthreads();
    }
    if (tid == 0) bsums[blockIdx.x] = red[0];
}

// single block, 256 threads: exclusive scan of bsums[nb] (nb <= 256) -> boffs, boffs[nb]=total
__global__ __launch_bounds__(256) void scan_bsums_kernel(const int* __restrict__ bsums, int nb,
                                                         int* __restrict__ boffs) {
    __shared__ int ws[4];
    int tid = threadIdx.x;
    int lane = tid & 63;
    int wv = tid >> 6;
    int orig = (tid < nb) ? bsums[tid] : 0;
    int v = orig;
#pragma unroll
    for (int off = 1; off < 64; off <<= 1) {
        int u = __shfl_up(v, off, 64);
        if (lane >= off) v += u;
    }
    if (lane == 63) ws[wv] = v;
    __syncthreads();
    int add = 0;
    for (int w = 0; w < wv; ++w) add += ws[w];
    v += add;
    if (tid < nb) boffs[tid] = v - orig;
    if (tid == nb - 1) boffs[nb] = v;
}

__global__ __launch_bounds__(256) void scan_write_kernel(const int* __restrict__ counts, int n,
                                                         const int* __restrict__ boffs, int nb,
                                                         int* __restrict__ out) {
    __shared__ int wsum[4];
    int tid = threadIdx.x;
    int lane = tid & 63;
    int wv = tid >> 6;
    int base = blockIdx.x * 2048 + tid * 8;

    int v[8];
    int s = 0;
#pragma unroll
    for (int i = 0; i < 8; ++i) {
        int idx = base + i;
        v[i] = (idx < n) ? counts[idx] : 0;
        s += v[i];
    }
    int incl = s;
#pragma unroll
    for (int off = 1; off < 64; off <<= 1) {
        int u = __shfl_up(incl, off, 64);
        if (lane >= off) incl += u;
    }
    if (lane == 63) wsum[wv] = incl;
    __syncthreads();
    int wexcl = 0;
    for (int w = 0; w < wv; ++w) wexcl += wsum[w];

    int run = boffs[blockIdx.x] + wexcl + (incl - s);
#pragma unroll
    for (int i = 0; i < 8; ++i) {
        int idx = base + i;
        if (idx < n) out[idx] = run;
        run += v[i];
    }
    if (blockIdx.x == 0 && tid == 0) out[n] = boffs[nb];
}

__global__ __launch_bounds__(256) void partition_kernel(const int* __restrict__ src,
                                                        const int* __restrict__ dst,
                                                        const float* __restrict__ w, int E,
                                                        int nbuck, int per,
                                                        const int* __restrict__ gofs,
                                                        uint2* __restrict__ coarse) {
    __shared__ int cur[1024];
    for (int i = threadIdx.x; i < nbuck; i += 256)
        cur[i] = gofs[(size_t)i * NBLK + blockIdx.x];
    __syncthreads();
    int b0 = blockIdx.x * per;
    int b1 = min(E, b0 + per);
    int e = b0 + threadIdx.x * 4;
    for (; e + 4 <= b1; e += 1024) {
        int4 d4 = *reinterpret_cast<const int4*>(&dst[e]);
        int4 s4 = *reinterpret_cast<const int4*>(&src[e]);
        float4 w4 = *reinterpret_cast<const float4*>(&w[e]);
        int p0 = atomicAdd(&cur[d4.x >> 7], 1);
        int p1 = atomicAdd(&cur[d4.y >> 7], 1);
        int p2 = atomicAdd(&cur[d4.z >> 7], 1);
        int p3 = atomicAdd(&cur[d4.w >> 7], 1);
        coarse[p0] = make_uint2((unsigned)s4.x | ((unsigned)(d4.x & 127) << 17), __float_as_uint(w4.x));
        coarse[p1] = make_uint2((unsigned)s4.y | ((unsigned)(d4.y & 127) << 17), __float_as_uint(w4.y));
        coarse[p2] = make_uint2((unsigned)s4.z | ((unsigned)(d4.z & 127) << 17), __float_as_uint(w4.z));
        coarse[p3] = make_uint2((unsigned)s4.w | ((unsigned)(d4.w & 127) << 17), __float_as_uint(w4.w));
    }
    for (; e < b1; ++e) {
        int d = dst[e];
        int pos = atomicAdd(&cur[d >> 7], 1);
        coarse[pos] = make_uint2((unsigned)src[e] | ((unsigned)(d & 127) << 17),
                                 __float_as_uint(w[e]));
    }
}

// One workgroup per bucket: build exact per-node CSR for its 128 nodes.
__global__ __launch_bounds__(256) void fine_kernel(const uint2* __restrict__ coarse,
                                                   const int* __restrict__ gofs, int N, int E,
                                                   int* __restrict__ row_ptr,
                                                   int* __restrict__ src_s,
                                                   float* __restrict__ w_s) {
    __shared__ uint2 stash[FCAP];
    __shared__ int hist[128];
    __shared__ int excl[128];
    int b = blockIdx.x;
    int gstart = gofs[(size_t)b * NBLK];
    int gend = gofs[(size_t)(b + 1) * NBLK];
    int cnt = gend - gstart;
    int tid = threadIdx.x;
    if (tid < 128) hist[tid] = 0;
    __syncthreads();
    for (int i = tid; i < cnt; i += 256) {
        uint2 e = coarse[gstart + i];
        if (i < FCAP) stash[i] = e;
        atomicAdd(&hist[(e.x >> 17) & 127], 1);
    }
    __syncthreads();
    if (tid < 64) {
        int a = hist[tid];
        int c = hist[tid + 64];
        int ia = a, ic = c;
#pragma unroll
        for (int off = 1; off < 64; off <<= 1) {
            int u = __shfl_up(ia, off, 64);
            if (tid >= off) ia += u;
            u = __shfl_up(ic, off, 64);
            if (tid >= off) ic += u;
        }
        int totA = __shfl(ia, 63, 64);
        excl[tid] = ia - a;
        excl[tid + 64] = totA + ic - c;
    }
    __syncthreads();
    int node0 = b << 7;
    if (tid < 128 && node0 + tid < N) row_ptr[node0 + tid] = gstart + excl[tid];
    if (b == 0 && tid == 0) row_ptr[N] = E;
    if (tid < 128) hist[tid] = excl[tid];   // reuse as cursor
    __syncthreads();
    for (int i = tid; i < cnt; i += 256) {
        uint2 e = (i < FCAP) ? stash[i] : coarse[gstart + i];
        int dl = (e.x >> 17) & 127;
        int pos = atomicAdd(&hist[dl], 1);
        src_s[gstart + pos] = (int)(e.x & 0x1FFFFu);
        w_s[gstart + pos] = __uint_as_float(e.y);
    }
}

// ---------------- converts ----------------
__global__ void convert_f32_bf16(const float* __restrict__ x, unsigned short* __restrict__ xb,
                                 size_t n4) {
    size_t stride = (size_t)gridDim.x * blockDim.x;
    for (size_t i = (size_t)blockIdx.x * blockDim.x + threadIdx.x; i < n4; i += stride) {
        float4 v = reinterpret_cast<const float4*>(x)[i];
        ushort4 o = make_ushort4(f32_to_bf16(v.x), f32_to_bf16(v.y), f32_to_bf16(v.z),
                                 f32_to_bf16(v.w));
        reinterpret_cast<ushort4*>(xb)[i] = o;
    }
}

// WT[n][k] = bf16(W[k][n]); grid (N/32, K/32), block 256
__global__ __launch_bounds__(256) void transpose_w_bf16(const float* __restrict__ W,
                                                        unsigned short* __restrict__ WT,
                                                        int K, int N) {
    __shared__ float t[32][33];
    int n0 = blockIdx.x * 32, k0 = blockIdx.y * 32;
    int tx = threadIdx.x & 31;
    int ty = threadIdx.x >> 5;  // 0..7
#pragma unroll
    for (int i = 0; i < 32; i += 8)
        t[ty + i][tx] = W[(size_t)(k0 + ty + i) * N + n0 + tx];
    __syncthreads();
#pragma unroll
    for (int i = 0; i < 32; i += 8)
        WT[(size_t)(n0 + ty + i) * K + k0 + tx] = f32_to_bf16(t[tx][ty + i]);
}

// ---------------- SpMM (bf16 rows): out[node] = bf16( sum_e w_e * X[src_e] ) ----------------
__global__ __launch_bounds__(256) void spmm_csr_bf16(const unsigned short* __restrict__ X,
                                                     const int* __restrict__ src_s,
                                                     const float* __restrict__ w_s,
                                                     const int* __restrict__ row_ptr,
                                                     unsigned short* __restrict__ out, int n) {
    int node = blockIdx.x * 4 + (threadIdx.x >> 6);
    if (node >= n) return;
    const int lane = threadIdx.x & 63;
    const int grp = lane >> 4;   // 0..3
    const int q = lane & 15;     // 16B chunk

    int beg = row_ptr[node];
    int end = row_ptr[node + 1];

    float acc[8];
#pragma unroll
    for (int j = 0; j < 8; ++j) acc[j] = 0.f;

    for (int e0 = beg; e0 < end; e0 += 64) {
        int cnt = min(64, end - e0);
        int s = 0;
        float ww = 0.f;
        if (lane < cnt) {
            s = src_s[e0 + lane];
            ww = w_s[e0 + lane];
        }

        int i = 0;
        for (; i + 16 <= cnt; i += 16) {
            int sx[4];
            float wx[4];
#pragma unroll
            for (int u = 0; u < 4; ++u) {
                sx[u] = __shfl(s, i + u * 4 + grp, 64);
                wx[u] = __shfl(ww, i + u * 4 + grp, 64);
            }
            uint4 v[4];
#pragma unroll
            for (int u = 0; u < 4; ++u)
                v[u] = *reinterpret_cast<const uint4*>(&X[(size_t)sx[u] * NHID + q * 8]);
#pragma unroll
            for (int u = 0; u < 4; ++u) {
                unsigned pw;
                pw = v[u].x;
                acc[0] += wx[u] * __uint_as_float(pw << 16);
                acc[1] += wx[u] * __uint_as_float(pw & 0xffff0000u);
                pw = v[u].y;
                acc[2] += wx[u] * __uint_as_float(pw << 16);
                acc[3] += wx[u] * __uint_as_float(pw & 0xffff0000u);
                pw = v[u].z;
                acc[4] += wx[u] * __uint_as_float(pw << 16);
                acc[5] += wx[u] * __uint_as_float(pw & 0xffff0000u);
                pw = v[u].w;
                acc[6] += wx[u] * __uint_as_float(pw << 16);
                acc[7] += wx[u] * __uint_as_float(pw & 0xffff0000u);
            }
        }
        for (; i + 4 <= cnt; i += 4) {
            int sx = __shfl(s, i + grp, 64);
            float wx = __shfl(ww, i + grp, 64);
            uint4 v = *reinterpret_cast<const uint4*>(&X[(size_t)sx * NHID + q * 8]);
            unsigned pw;
            pw = v.x;
            acc[0] += wx * __uint_as_float(pw << 16);
            acc[1] += wx * __uint_as_float(pw & 0xffff0000u);
            pw = v.y;
            acc[2] += wx * __uint_as_float(pw << 16);
            acc[3] += wx * __uint_as_float(pw & 0xffff0000u);
            pw = v.z;
            acc[4] += wx * __uint_as_float(pw << 16);
            acc[5] += wx * __uint_as_float(pw & 0xffff0000u);
            pw = v.w;
            acc[6] += wx * __uint_as_float(pw << 16);
            acc[7] += wx * __uint_as_float(pw & 0xffff0000u);
        }
        if (i < cnt) {
            int idx = i + grp;
            int sx = __shfl(s, idx, 64);
            float wx = __shfl(ww, idx, 64);
            if (idx < cnt) {
                uint4 v = *reinterpret_cast<const uint4*>(&X[(size_t)sx * NHID + q * 8]);
                unsigned pw;
                pw = v.x;
                acc[0] += wx * __uint_as_float(pw << 16);
                acc[1] += wx * __uint_as_float(pw & 0xffff0000u);
                pw = v.y;
                acc[2] += wx * __uint_as_float(pw << 16);
                acc[3] += wx * __uint_as_float(pw & 0xffff0000u);
                pw = v.z;
                acc[4] += wx * __uint_as_float(pw << 16);
                acc[5] += wx * __uint_as_float(pw & 0xffff0000u);
                pw = v.w;
                acc[6] += wx * __uint_as_float(pw << 16);
                acc[7] += wx * __uint_as_float(pw & 0xffff0000u);
            }
        }
    }

#pragma unroll
    for (int j = 0; j < 8; ++j) {
        acc[j] += __shfl_xor(acc[j], 16, 64);
        acc[j] += __shfl_xor(acc[j], 32, 64);
    }

    if (grp == 0) {
        short8v o;
#pragma unroll
        for (int j = 0; j < 8; ++j) o[j] = (short)f32_to_bf16(acc[j]);
        *reinterpret_cast<short8v*>(&out[(size_t)node * NHID + q * 8]) = o;
    }
}

// ---------------- MFMA GEMM + bias + ReLU ----------------
template <int DOUT, bool OUT_BF16>
__global__ __launch_bounds__(256) void gemm_mfma(const unsigned short* __restrict__ Xb,
                                                 const unsigned short* __restrict__ WT,
                                                 const float* __restrict__ bias,
                                                 void* __restrict__ outv, int nrows) {
    __shared__ unsigned short Ab[128 * 128];
    __shared__ unsigned short Bb[128 * 128];
    const int row0 = blockIdx.x * 128;
    const int col0 = blockIdx.y * 128;
    const int tid = threadIdx.x;
    const int lane = tid & 63;
    const int wid = tid >> 6;
    const int waveM = wid >> 1;
    const int waveN = wid & 1;

    {
        const int c = tid & 15;
        int r = tid >> 4;
#pragma unroll
        for (int p = 0; p < 8; ++p, r += 16) {
            int row = row0 + r;
            uint4 va = make_uint4(0, 0, 0, 0);
            if (row < nrows) va = *reinterpret_cast<const uint4*>(&Xb[(size_t)row * 128 + c * 8]);
            uint4 vb = *reinterpret_cast<const uint4*>(&WT[(size_t)(col0 + r) * 128 + c * 8]);
            int cs = (c ^ (r & 15)) * 8;
            *reinterpret_cast<uint4*>(&Ab[r * 128 + cs]) = va;
            *reinterpret_cast<uint4*>(&Bb[r * 128 + cs]) = vb;
        }
    }
    __syncthreads();

    const int lr = lane & 15;
    const int lk = lane >> 4;

    f32x4 acc[4][4];
#pragma unroll
    for (int m = 0; m < 4; ++m)
#pragma unroll
        for (int nn = 0; nn < 4; ++nn) acc[m][nn] = (f32x4){0.f, 0.f, 0.f, 0.f};

#pragma unroll
    for (int ks = 0; ks < 4; ++ks) {
        short8v a[4], b[4];
#pragma unroll
        for (int m = 0; m < 4; ++m) {
            int row = waveM * 64 + m * 16 + lr;
            int c16 = (ks * 4 + lk) ^ (row & 15);
            a[m] = *reinterpret_cast<const short8v*>(&Ab[row * 128 + c16 * 8]);
        }
#pragma unroll
        for (int nn = 0; nn < 4; ++nn) {
            int rowb = waveN * 64 + nn * 16 + lr;
            int c16 = (ks * 4 + lk) ^ (rowb & 15);
            b[nn] = *reinterpret_cast<const short8v*>(&Bb[rowb * 128 + c16 * 8]);
        }
#pragma unroll
        for (int m = 0; m < 4; ++m)
#pragma unroll
            for (int nn = 0; nn < 4; ++nn)
                acc[m][nn] = __builtin_amdgcn_mfma_f32_16x16x32_bf16(a[m], b[nn], acc[m][nn], 0, 0, 0);
    }

    float bj[4];
#pragma unroll
    for (int nn = 0; nn < 4; ++nn) bj[nn] = bias[col0 + waveN * 64 + nn * 16 + lr];

#pragma unroll
    for (int m = 0; m < 4; ++m) {
        int rbase = row0 + waveM * 64 + m * 16 + lk * 4;
#pragma unroll
        for (int reg = 0; reg < 4; ++reg) {
            int r = rbase + reg;
            if (r >= nrows) continue;
#pragma unroll
            for (int nn = 0; nn < 4; ++nn) {
                int cidx = col0 + waveN * 64 + nn * 16 + lr;
                float v = fmaxf(acc[m][nn][reg] + bj[nn], 0.f);
                if (OUT_BF16)
                    ((unsigned short*)outv)[(size_t)r * DOUT + cidx] = f32_to_bf16(v);
                else
                    ((float*)outv)[(size_t)r * DOUT + cidx] = v;
            }
        }
    }
}

extern "C" void kernel_launch(void* const* d_in, const int* in_sizes, int n_in,
                              void* d_out, int out_size, void* d_ws, size_t ws_size,
                              hipStream_t stream) {
    const float* x  = (const float*)d_in[0];
    const float* ew = (const float*)d_in[1];
    const float* W1 = (const float*)d_in[2];
    const float* b1 = (const float*)d_in[3];
    const float* W2 = (const float*)d_in[4];
    const float* b2 = (const float*)d_in[5];
    const int*   ei = (const int*)d_in[6];

    const int N = in_sizes[0] / NHID;   // 100000 (must be < 131072 for 17-bit src packing)
    const int E = in_sizes[1];          // 1600000
    const int* src = ei;
    const int* dst = ei + E;

    const int nbuck = (N + 127) >> 7;                  // 782
    const int n2 = nbuck * NBLK;                       // 400384 scan elements
    const int nb2 = (n2 + 2047) / 2048;                // 196 (<=256)
    const int per = (((E + NBLK - 1) / NBLK) + 3) & ~3;  // edges per partition block, x4 aligned

    auto align256 = [](size_t v) { return (v + 255) & ~(size_t)255; };
    char* p = (char*)d_ws;
    unsigned short* xb  = (unsigned short*)p; p += align256((size_t)N * NHID * 2);
    unsigned short* gb  = (unsigned short*)p; p += align256((size_t)N * NHID * 2);
    unsigned short* hb  = (unsigned short*)p; p += align256((size_t)N * NHID * 2);
    unsigned short* W1T = (unsigned short*)p; p += align256((size_t)128 * 128 * 2);
    unsigned short* W2T = (unsigned short*)p; p += align256((size_t)256 * 128 * 2);
    int*   ghist   = (int*)p;   p += align256((size_t)(n2 + 1) * 4);
    int*   gofs    = (int*)p;   p += align256((size_t)(n2 + 1) * 4);
    int*   row_ptr = (int*)p;   p += align256((size_t)(N + 1) * 4);
    int*   src_s   = (int*)p;   p += align256((size_t)E * 4);
    float* w_s     = (float*)p; p += align256((size_t)E * 4);
    uint2* coarse  = (uint2*)p; p += align256((size_t)E * 8);
    int*   bsums   = (int*)p;   p += align256((size_t)256 * 4);
    int*   boffs   = (int*)p;   p += align256((size_t)260 * 4);

    // ---- CSR build: coarse hist -> scan -> partition -> fine ----
    coarse_hist_kernel<<<NBLK, 256, 0, stream>>>(dst, E, nbuck, per, ghist);
    block_sum_kernel<<<nb2, 256, 0, stream>>>(ghist, n2, bsums);
    scan_bsums_kernel<<<1, 256, 0, stream>>>(bsums, nb2, boffs);
    scan_write_kernel<<<nb2, 256, 0, stream>>>(ghist, n2, boffs, nb2, gofs);
    partition_kernel<<<NBLK, 256, 0, stream>>>(src, dst, ew, E, nbuck, per, gofs, coarse);
    fine_kernel<<<nbuck, 256, 0, stream>>>(coarse, gofs, N, E, row_ptr, src_s, w_s);

    // ---- precision converts ----
    convert_f32_bf16<<<2048, 256, 0, stream>>>(x, xb, (size_t)N * NHID / 4);
    {
        dim3 g1(128 / 32, 128 / 32);
        transpose_w_bf16<<<g1, 256, 0, stream>>>(W1, W1T, 128, 128);
        dim3 g2(256 / 32, 128 / 32);
        transpose_w_bf16<<<g2, 256, 0, stream>>>(W2, W2T, 128, 256);
    }

    // ---- layer 1: h = relu((A @ x) @ W1 + b1) ----
    spmm_csr_bf16<<<(N + 3) / 4, 256, 0, stream>>>(xb, src_s, w_s, row_ptr, gb, N);
    {
        dim3 grid((N + 127) / 128, 1);
        gemm_mfma<128, true><<<grid, 256, 0, stream>>>(gb, W1T, b1, hb, N);
    }

    // ---- layer 2: out = relu((A @ h) @ W2 + b2) ----
    spmm_csr_bf16<<<(N + 3) / 4, 256, 0, stream>>>(hb, src_s, w_s, row_ptr, gb, N);
    {
        dim3 grid((N + 127) / 128, 2);
        gemm_mfma<256, false><<<grid, 256, 0, stream>>>(gb, W2T, b2, (float*)d_out, N);
    }
}